// Round 18
// baseline (116.483 us; speedup 1.0000x reference)
//
#include <hip/hip_runtime.h>
#include <hip/hip_fp16.h>
#include <math.h>

__device__ __forceinline__ float lrelu02(float x) { return x > 0.f ? x : 0.2f * x; }

typedef _Float16 v8h __attribute__((ext_vector_type(8)));
typedef float f32x4 __attribute__((ext_vector_type(4)));

#define ESHIFT 10.0f   // constant shift replacing global max (alpha is ratio-invariant)
#define NCHUNK 128     // sort chunks (blocks in P1/P3)

// ============ CSR build: tile counting sort, NO global atomics ============
__global__ __launch_bounds__(1024) void sort_hist_kernel(
    const int* __restrict__ trg, int* __restrict__ H, int E, int nbk, int chunk)
{
    __shared__ int hist[256];
    int c = blockIdx.x, t = threadIdx.x;
    if (t < 256) hist[t] = 0;
    __syncthreads();
    int e0 = c * chunk, e1 = min(e0 + chunk, E);
    for (int i = e0 + t; i < e1; i += 1024)
        atomicAdd(&hist[trg[i] >> 8], 1);
    __syncthreads();
    if (t < nbk) H[c * nbk + t] = hist[t];
}

__global__ __launch_bounds__(256) void sort_scan_kernel(
    const int* __restrict__ H, int* __restrict__ base,
    int* __restrict__ bktstart, int* __restrict__ rowptr,
    int nbk, int E)
{
    __shared__ int sm[256];
    int t = threadIdx.x;
    int hv[NCHUNK];
    int tot = 0;
    if (t < nbk) {
#pragma unroll
        for (int c = 0; c < NCHUNK; ++c) hv[c] = H[c * nbk + t];
#pragma unroll
        for (int c = 0; c < NCHUNK; ++c) tot += hv[c];
    }
    sm[t] = tot;
    __syncthreads();
    for (int off = 1; off < 256; off <<= 1) {
        int x = (t >= off) ? sm[t - off] : 0;
        __syncthreads();
        sm[t] += x;
        __syncthreads();
    }
    int excl = sm[t] - tot;
    if (t < nbk) {
        bktstart[t] = excl;
        int run = excl;
#pragma unroll
        for (int c = 0; c < NCHUNK; ++c) { base[c * nbk + t] = run; run += hv[c]; }
    }
    if (t == 0) { bktstart[nbk] = E; rowptr[nbk * 256] = E; }
}

__global__ __launch_bounds__(1024) void sort_scatter_kernel(
    const int* __restrict__ src, const int* __restrict__ trg,
    const int* __restrict__ base, int2* __restrict__ stage,
    int E, int nbk, int chunk)
{
    __shared__ int cur[256];
    int c = blockIdx.x, t = threadIdx.x;
    if (t < nbk) cur[t] = base[c * nbk + t];
    __syncthreads();
    int e0 = c * chunk, e1 = min(e0 + chunk, E);
    for (int i = e0 + t; i < e1; i += 1024) {
        int tg = trg[i];
        int pos = atomicAdd(&cur[tg >> 8], 1);
        stage[pos] = make_int2(src[i], tg);
    }
}

__global__ __launch_bounds__(256) void sort_finalize_kernel(
    const int2* __restrict__ stage, const int* __restrict__ bktstart,
    int* __restrict__ rowptr, int* __restrict__ colsrc, int nbk)
{
    __shared__ int hist[256];
    __shared__ int sm[256];
    __shared__ int cur[256];
    int b = blockIdx.x, t = threadIdx.x;
    int s0 = bktstart[b], cnt = bktstart[b + 1] - s0;
    hist[t] = 0;
    __syncthreads();
    for (int i = t; i < cnt; i += 256)
        atomicAdd(&hist[stage[s0 + i].y & 255], 1);
    __syncthreads();
    int h = hist[t];
    sm[t] = h;
    __syncthreads();
    for (int off = 1; off < 256; off <<= 1) {
        int x = (t >= off) ? sm[t - off] : 0;
        __syncthreads();
        sm[t] += x;
        __syncthreads();
    }
    int excl = sm[t] - h;
    cur[t] = s0 + excl;
    rowptr[b * 256 + t] = s0 + excl;
    __syncthreads();
    for (int i = t; i < cnt; i += 256) {
        int2 p = stage[s0 + i];
        int pos = atomicAdd(&cur[p.y & 255], 1);
        colsrc[pos] = p.x;
    }
}

// ---------------- W pre-pack (fp16): wt[c][k] + folded score matrix mtg ----------
__global__ __launch_bounds__(256) void wconv_kernel(
    const float* __restrict__ w0, const float* __restrict__ asrc0,
    const float* __restrict__ atrg0, _Float16* __restrict__ wt,
    _Float16* __restrict__ mtg)
{
    int i = blockIdx.x * 256 + threadIdx.x;
    if (i < 16384) {
        int c = i >> 7, k = i & 127;
        int h = c >> 4, o = c & 15;
        wt[i] = (_Float16)w0[h * 2048 + k * 16 + o];
    } else if (i < 16384 + 2048) {
        int m = i - 16384;
        int j = m >> 7, k = m & 127;
        int h = j & 7;
        const float* av = (j < 8) ? asrc0 : atrg0;
        float s = 0.f;
#pragma unroll
        for (int o = 0; o < 16; ++o) s += w0[h * 2048 + k * 16 + o] * av[h * 16 + o];
        mtg[m] = (_Float16)s;
    }
}

// ---------------- Layer-0 projection via MFMA (f16 in, f32 acc) ----------------
__device__ __forceinline__ v8h cvt8(float4 lo, float4 hi) {
    v8h r;
    r[0] = (_Float16)lo.x; r[1] = (_Float16)lo.y; r[2] = (_Float16)lo.z; r[3] = (_Float16)lo.w;
    r[4] = (_Float16)hi.x; r[5] = (_Float16)hi.y; r[6] = (_Float16)hi.z; r[7] = (_Float16)hi.w;
    return r;
}

__global__ __launch_bounds__(256) void gemm0_kernel(
    const float* __restrict__ stat, const float* __restrict__ dyn0,
    const float* __restrict__ dyn1, const float4* __restrict__ wt4g,
    const _Float16* __restrict__ mtg,
    __half* __restrict__ hp_half, float* __restrict__ s0, float* __restrict__ t0,
    int n_nodes)
{
    __shared__ char wt_s[32768];   // 128 rows (c) x 256B, XOR-swizzled
    int t = threadIdx.x;
    int nb = blockIdx.x * 64;

#pragma unroll
    for (int j = 0; j < 8; ++j) {
        int i = t + j * 256;
        int c = i >> 4;
        int dst = (i * 16) ^ ((c & 7) << 4);
        *reinterpret_cast<float4*>(wt_s + dst) = wt4g[i];
    }
    __syncthreads();

    int l = t & 63, w = t >> 6;
    int cl = l & 15, klo = l >> 4;
    int rowbase = w * 16;
    int rg = min(nb + rowbase + cl, n_nodes - 1);

    v8h a[4];
    {
        float4 lo, hi;
        lo = *reinterpret_cast<const float4*>(&dyn0[(size_t)rg * 32 + klo * 8]);
        hi = *reinterpret_cast<const float4*>(&dyn0[(size_t)rg * 32 + klo * 8 + 4]);
        a[0] = cvt8(lo, hi);
        lo = *reinterpret_cast<const float4*>(&dyn1[(size_t)rg * 32 + klo * 8]);
        hi = *reinterpret_cast<const float4*>(&dyn1[(size_t)rg * 32 + klo * 8 + 4]);
        a[1] = cvt8(lo, hi);
        lo = *reinterpret_cast<const float4*>(&stat[(size_t)rg * 64 + klo * 8]);
        hi = *reinterpret_cast<const float4*>(&stat[(size_t)rg * 64 + klo * 8 + 4]);
        a[2] = cvt8(lo, hi);
        lo = *reinterpret_cast<const float4*>(&stat[(size_t)rg * 64 + 32 + klo * 8]);
        hi = *reinterpret_cast<const float4*>(&stat[(size_t)rg * 64 + 32 + klo * 8 + 4]);
        a[3] = cvt8(lo, hi);
    }

    f32x4 sacc = {0.f, 0.f, 0.f, 0.f};
#pragma unroll
    for (int kk = 0; kk < 4; ++kk) {
        v8h b = *reinterpret_cast<const v8h*>(&mtg[(size_t)cl * 128 + kk * 32 + klo * 8]);
        sacc = __builtin_amdgcn_mfma_f32_16x16x32_f16(a[kk], b, sacc, 0, 0, 0);
    }

    f32x4 acc[8];
#pragma unroll
    for (int cb = 0; cb < 8; ++cb) {
        f32x4 c = {0.f, 0.f, 0.f, 0.f};
#pragma unroll
        for (int kk = 0; kk < 4; ++kk) {
            int cc = cb * 16 + cl;
            int byte = (cc * 256 + kk * 64 + klo * 16) ^ ((cl & 7) << 4);
            v8h b = *reinterpret_cast<const v8h*>(wt_s + byte);
            c = __builtin_amdgcn_mfma_f32_16x16x32_f16(a[kk], b, c, 0, 0, 0);
        }
        acc[cb] = c;
    }

#pragma unroll
    for (int r = 0; r < 4; ++r) {
        int node = nb + rowbase + klo * 4 + r;
        if (node < n_nodes) {
#pragma unroll
            for (int cb = 0; cb < 8; ++cb)
                hp_half[(size_t)node * 128 + cb * 16 + cl] = (__half)acc[cb][r];
            if (cl < 8) s0[node * 8 + cl]     = sacc[r];
            else        t0[node * 8 + cl - 8] = sacc[r];
        }
    }
}

// ---------------- Layer-0 aggregate: one WAVE per target node ----------------
// Full chunks (m==64) use a software-pipelined 8-edge-batch fast path to keep
// ~8 gather misses in flight per wave; tails use the scalar path.
#define CH 64
__global__ __launch_bounds__(256) void node_accum0_kernel(
    const int* __restrict__ rowptr, const int* __restrict__ colsrc,
    const float* __restrict__ s0, const float* __restrict__ t0,
    const __half2* __restrict__ hp0h, const float* __restrict__ w1,
    const float* __restrict__ asrc1, const float* __restrict__ atrg1,
    float4* __restrict__ pk1, float* __restrict__ t1, int n_nodes)
{
    __shared__ int   se_s[4][CH];
    __shared__ float p_s[4][CH * 8];

    int w = threadIdx.x >> 6;
    int l = threadIdx.x & 63;
    int n = blockIdx.x * 4 + w;
    if (n >= n_nodes) return;

    int start = rowptr[n];
    int deg = rowptr[n + 1] - start;
    int hl = l & 7;
    int g  = l >> 5;
    int j  = l & 31;
    int hc2 = j >> 2;
    float tval = t0[n * 8 + hl];
    const float* pw = p_s[w];

    float a0 = 0.f, a1 = 0.f, a2 = 0.f, a3 = 0.f, dsum = 0.f;
    for (int chunk = 0; chunk < deg; chunk += CH) {
        int m = min(CH, deg - chunk);
        se_s[w][l] = (l < m) ? colsrc[start + chunk + l] : 0;
        __builtin_amdgcn_wave_barrier();
        int iters = (m + 7) >> 3;
        for (int r = 0; r < iters; ++r) {
            int e = r * 8 + (l >> 3);
            float p = 0.f;
            if (e < m) {
                int se = se_s[w][e];
                float x = s0[se * 8 + hl] + tval;
                p = __expf(lrelu02(x) - ESHIFT);
            }
            p_s[w][r * 64 + l] = p;
            dsum += p;
        }
        __builtin_amdgcn_wave_barrier();

        if (m == CH) {
            // fast path: 8 batches of 8 edges, loads pipelined one batch ahead
            float2 cur[4], nxt[4];
#pragma unroll
            for (int q = 0; q < 4; ++q) {
                int se = se_s[w][q * 2 + g];
                cur[q] = *reinterpret_cast<const float2*>(&hp0h[(size_t)se * 64 + j * 2]);
            }
#pragma unroll
            for (int b = 0; b < 8; ++b) {
                if (b < 7) {
#pragma unroll
                    for (int q = 0; q < 4; ++q) {
                        int se = se_s[w][(b + 1) * 8 + q * 2 + g];
                        nxt[q] = *reinterpret_cast<const float2*>(&hp0h[(size_t)se * 64 + j * 2]);
                    }
                }
#pragma unroll
                for (int q = 0; q < 4; ++q) {
                    float p = pw[(b * 8 + q * 2 + g) * 8 + hc2];
                    const __half2* hh = reinterpret_cast<const __half2*>(&cur[q]);
                    float2 f0 = __half22float2(hh[0]), f1 = __half22float2(hh[1]);
                    a0 += f0.x * p; a1 += f0.y * p; a2 += f1.x * p; a3 += f1.y * p;
                }
#pragma unroll
                for (int q = 0; q < 4; ++q) cur[q] = nxt[q];
            }
        } else {
            int e = 0;
            for (; e + 4 <= m; e += 4) {
                int sa = se_s[w][e + g];
                int sb = se_s[w][e + 2 + g];
                float2 ra = *reinterpret_cast<const float2*>(&hp0h[(size_t)sa * 64 + j * 2]);
                float2 rb = *reinterpret_cast<const float2*>(&hp0h[(size_t)sb * 64 + j * 2]);
                float pa = pw[(e + g) * 8 + hc2];
                float pb = pw[(e + 2 + g) * 8 + hc2];
                const __half2* ha = reinterpret_cast<const __half2*>(&ra);
                const __half2* hb = reinterpret_cast<const __half2*>(&rb);
                float2 fa0 = __half22float2(ha[0]), fa1 = __half22float2(ha[1]);
                float2 fb0 = __half22float2(hb[0]), fb1 = __half22float2(hb[1]);
                a0 += fa0.x * pa; a1 += fa0.y * pa; a2 += fa1.x * pa; a3 += fa1.y * pa;
                a0 += fb0.x * pb; a1 += fb0.y * pb; a2 += fb1.x * pb; a3 += fb1.y * pb;
            }
            for (; e < m; e += 2) {
                int ee = e + g;
                int se = se_s[w][ee];
                float2 ra = *reinterpret_cast<const float2*>(&hp0h[(size_t)se * 64 + j * 2]);
                float p = pw[ee * 8 + hc2];
                const __half2* ha = reinterpret_cast<const __half2*>(&ra);
                float2 f0 = __half22float2(ha[0]), f1 = __half22float2(ha[1]);
                a0 += f0.x * p; a1 += f0.y * p; a2 += f1.x * p; a3 += f1.y * p;
            }
        }
        __builtin_amdgcn_wave_barrier();
    }

    a0 += __shfl_xor(a0, 32);
    a1 += __shfl_xor(a1, 32);
    a2 += __shfl_xor(a2, 32);
    a3 += __shfl_xor(a3, 32);

    dsum += __shfl_xor(dsum, 8);
    dsum += __shfl_xor(dsum, 16);
    dsum += __shfl_xor(dsum, 32);
    float denom = __shfl(dsum, hc2);
    float inv = 1.f / (denom + 1e-16f);
    float v0 = a0 * inv; v0 = v0 > 0.f ? v0 : expm1f(v0);
    float v1 = a1 * inv; v1 = v1 > 0.f ? v1 : expm1f(v1);
    float v2 = a2 * inv; v2 = v2 > 0.f ? v2 : expm1f(v2);
    float v3 = a3 * inv; v3 = v3 > 0.f ? v3 : expm1f(v3);

    float4 wv0 = *reinterpret_cast<const float4*>(&w1[j * 8]);
    float4 wv1 = *reinterpret_cast<const float4*>(&w1[j * 8 + 4]);
    float r0 = v0 * wv0.x + v1 * wv0.z + v2 * wv1.x + v3 * wv1.z;
    float r1 = v0 * wv0.y + v1 * wv0.w + v2 * wv1.y + v3 * wv1.w;
#pragma unroll
    for (int off = 16; off > 0; off >>= 1) {
        r0 += __shfl_down(r0, off);
        r1 += __shfl_down(r1, off);
    }
    if (l == 0) {
        float s1v = r0 * asrc1[0] + r1 * asrc1[1];
        float t1v = r0 * atrg1[0] + r1 * atrg1[1];
        float4 pk; pk.x = r0; pk.y = r1; pk.z = s1v; pk.w = 0.f;
        pk1[n] = pk;
        t1[n] = t1v;
    }
}

// ---------------- Layer-1 aggregate + mean + log_softmax -> out ----------------
__global__ __launch_bounds__(256) void node_accum1_kernel(
    const int* __restrict__ rowptr, const int* __restrict__ colsrc,
    const float4* __restrict__ pk1, const float* __restrict__ t1,
    float* __restrict__ out, int n_nodes)
{
    int lane = threadIdx.x & 63;
    int n = blockIdx.x * 4 + (threadIdx.x >> 6);
    if (n >= n_nodes) return;
    int start = rowptr[n], deg = rowptr[n + 1] - start;
    float tn = t1[n];
    float d = 0.f, a0 = 0.f, a1 = 0.f;
    for (int i = lane; i < deg; i += 64) {
        int se = colsrc[start + i];
        float4 q = pk1[se];
        float p = __expf(lrelu02(q.z + tn) - ESHIFT);
        d += p;
        a0 += p * q.x;
        a1 += p * q.y;
    }
#pragma unroll
    for (int off = 32; off > 0; off >>= 1) {
        d  += __shfl_down(d, off);
        a0 += __shfl_down(a0, off);
        a1 += __shfl_down(a1, off);
    }
    if (lane == 0) {
        float inv = 1.f / (d + 1e-16f);
        float x0 = a0 * inv, x1 = a1 * inv;
        float m = fmaxf(x0, x1);
        float lse = m + logf(__expf(x0 - m) + __expf(x1 - m));
        out[n * 2 + 0] = x0 - lse;
        out[n * 2 + 1] = x1 - lse;
    }
}

extern "C" void kernel_launch(void* const* d_in, const int* in_sizes, int n_in,
                              void* d_out, int out_size, void* d_ws, size_t ws_size,
                              hipStream_t stream) {
    const float* stat  = (const float*)d_in[0];
    const float* dyn0  = (const float*)d_in[1];
    const float* dyn1  = (const float*)d_in[2];
    const int*   src   = (const int*)d_in[3];
    const int*   trg   = (const int*)d_in[4];
    const float* w0    = (const float*)d_in[5];
    const float* asrc0 = (const float*)d_in[6];
    const float* atrg0 = (const float*)d_in[7];
    const float* w1    = (const float*)d_in[8];
    const float* asrc1 = (const float*)d_in[9];
    const float* atrg1 = (const float*)d_in[10];
    float* out = (float*)d_out;

    const int N = in_sizes[0] / 64;   // 50000
    const int E = in_sizes[3];        // 800000
    const int NBK = (N + 255) >> 8;   // 196 buckets of 256 nodes
    const int CHUNK = (E + NCHUNK - 1) / NCHUNK;
    const int NTB = (N + 63) >> 6;    // 782 gemm0 blocks (64 nodes each)

    // ---- workspace layout ----
    float* ws = (float*)d_ws;
    size_t off = 0;
    __half2* hp0h = (__half2*)(ws + off);
    int2*    stage = (int2*)(ws + off);
    off += (size_t)N * 64;
    float* s0  = ws + off; off += (size_t)N * 8;
    float* t0  = ws + off; off += (size_t)N * 8;
    float4* pk1 = (float4*)(ws + off); off += (size_t)N * 4;
    float* t1  = ws + off; off += (size_t)N;
    _Float16* wt  = (_Float16*)(ws + off); off += 8192;   // 32KB fp16 W^T [c][k]
    _Float16* mtg = (_Float16*)(ws + off); off += 1024;   // 4KB fp16 Bs^T [j][k]
    off = (off + 3) & ~(size_t)3;
    int* iws      = (int*)(ws + off);
    int* rowptr   = iws;                        // NBK*256 + 1
    int* colsrc   = rowptr + NBK * 256 + 1;     // E
    int* H        = colsrc + E;                 // NCHUNK*NBK
    int* basearr  = H + NCHUNK * NBK;           // NCHUNK*NBK
    int* bktstart = basearr + NCHUNK * NBK;     // NBK+1

    // ---- CSR build (tile counting sort, no global atomics) ----
    sort_hist_kernel<<<NCHUNK, 1024, 0, stream>>>(trg, H, E, NBK, CHUNK);
    sort_scan_kernel<<<1, 256, 0, stream>>>(H, basearr, bktstart, rowptr, NBK, E);
    sort_scatter_kernel<<<NCHUNK, 1024, 0, stream>>>(src, trg, basearr, stage, E, NBK, CHUNK);
    sort_finalize_kernel<<<NBK, 256, 0, stream>>>(stage, bktstart, rowptr, colsrc, NBK);

    // ---- W pre-pack (fp16 W^T + folded score matrix), then MFMA projection ----
    wconv_kernel<<<72, 256, 0, stream>>>(w0, asrc0, atrg0, wt, mtg);
    gemm0_kernel<<<NTB, 256, 0, stream>>>(
        stat, dyn0, dyn1, (const float4*)wt, mtg, (__half*)hp0h, s0, t0, N);

    // ---- layer 0 aggregate + ELU + W1 + layer-1 scores (wave per node) ----
    node_accum0_kernel<<<(N + 3) / 4, 256, 0, stream>>>(
        rowptr, colsrc, s0, t0, hp0h, w1, asrc1, atrg1, pk1, t1, N);

    // ---- layer 1 aggregate + mean + log_softmax ----
    node_accum1_kernel<<<(N + 3) / 4, 256, 0, stream>>>(
        rowptr, colsrc, pk1, t1, out, N);
}

// Round 19
// 103.072 us; speedup vs baseline: 1.1301x; 1.1301x over previous
//
#include <hip/hip_runtime.h>
#include <hip/hip_fp16.h>
#include <math.h>

__device__ __forceinline__ float lrelu02(float x) { return x > 0.f ? x : 0.2f * x; }

typedef _Float16 v8h __attribute__((ext_vector_type(8)));
typedef float f32x4 __attribute__((ext_vector_type(4)));

#define ESHIFT 10.0f   // constant shift replacing global max (alpha is ratio-invariant)
#define NCHUNK 128     // sort chunks (blocks in P1/P3)

// ============ CSR build: tile counting sort, NO global atomics ============
__global__ __launch_bounds__(1024) void sort_hist_kernel(
    const int* __restrict__ trg, int* __restrict__ H, int E, int nbk, int chunk)
{
    __shared__ int hist[256];
    int c = blockIdx.x, t = threadIdx.x;
    if (t < 256) hist[t] = 0;
    __syncthreads();
    int e0 = c * chunk, e1 = min(e0 + chunk, E);
    for (int i = e0 + t; i < e1; i += 1024)
        atomicAdd(&hist[trg[i] >> 8], 1);
    __syncthreads();
    if (t < nbk) H[c * nbk + t] = hist[t];
}

__global__ __launch_bounds__(256) void sort_scan_kernel(
    const int* __restrict__ H, int* __restrict__ base,
    int* __restrict__ bktstart, int* __restrict__ rowptr,
    int nbk, int E)
{
    __shared__ int sm[256];
    int t = threadIdx.x;
    int hv[NCHUNK];
    int tot = 0;
    if (t < nbk) {
#pragma unroll
        for (int c = 0; c < NCHUNK; ++c) hv[c] = H[c * nbk + t];
#pragma unroll
        for (int c = 0; c < NCHUNK; ++c) tot += hv[c];
    }
    sm[t] = tot;
    __syncthreads();
    for (int off = 1; off < 256; off <<= 1) {
        int x = (t >= off) ? sm[t - off] : 0;
        __syncthreads();
        sm[t] += x;
        __syncthreads();
    }
    int excl = sm[t] - tot;
    if (t < nbk) {
        bktstart[t] = excl;
        int run = excl;
#pragma unroll
        for (int c = 0; c < NCHUNK; ++c) { base[c * nbk + t] = run; run += hv[c]; }
    }
    if (t == 0) { bktstart[nbk] = E; rowptr[nbk * 256] = E; }
}

__global__ __launch_bounds__(1024) void sort_scatter_kernel(
    const int* __restrict__ src, const int* __restrict__ trg,
    const int* __restrict__ base, int2* __restrict__ stage,
    int E, int nbk, int chunk)
{
    __shared__ int cur[256];
    int c = blockIdx.x, t = threadIdx.x;
    if (t < nbk) cur[t] = base[c * nbk + t];
    __syncthreads();
    int e0 = c * chunk, e1 = min(e0 + chunk, E);
    for (int i = e0 + t; i < e1; i += 1024) {
        int tg = trg[i];
        int pos = atomicAdd(&cur[tg >> 8], 1);
        stage[pos] = make_int2(src[i], tg);
    }
}

__global__ __launch_bounds__(256) void sort_finalize_kernel(
    const int2* __restrict__ stage, const int* __restrict__ bktstart,
    int* __restrict__ rowptr, int* __restrict__ colsrc, int nbk)
{
    __shared__ int hist[256];
    __shared__ int sm[256];
    __shared__ int cur[256];
    int b = blockIdx.x, t = threadIdx.x;
    int s0 = bktstart[b], cnt = bktstart[b + 1] - s0;
    hist[t] = 0;
    __syncthreads();
    for (int i = t; i < cnt; i += 256)
        atomicAdd(&hist[stage[s0 + i].y & 255], 1);
    __syncthreads();
    int h = hist[t];
    sm[t] = h;
    __syncthreads();
    for (int off = 1; off < 256; off <<= 1) {
        int x = (t >= off) ? sm[t - off] : 0;
        __syncthreads();
        sm[t] += x;
        __syncthreads();
    }
    int excl = sm[t] - h;
    cur[t] = s0 + excl;
    rowptr[b * 256 + t] = s0 + excl;
    __syncthreads();
    for (int i = t; i < cnt; i += 256) {
        int2 p = stage[s0 + i];
        int pos = atomicAdd(&cur[p.y & 255], 1);
        colsrc[pos] = p.x;
    }
}

// ---------------- W pre-pack (fp16): wt[c][k] + folded score matrix mtg ----------
__global__ __launch_bounds__(256) void wconv_kernel(
    const float* __restrict__ w0, const float* __restrict__ asrc0,
    const float* __restrict__ atrg0, _Float16* __restrict__ wt,
    _Float16* __restrict__ mtg)
{
    int i = blockIdx.x * 256 + threadIdx.x;
    if (i < 16384) {
        int c = i >> 7, k = i & 127;
        int h = c >> 4, o = c & 15;
        wt[i] = (_Float16)w0[h * 2048 + k * 16 + o];
    } else if (i < 16384 + 2048) {
        int m = i - 16384;
        int j = m >> 7, k = m & 127;
        int h = j & 7;
        const float* av = (j < 8) ? asrc0 : atrg0;
        float s = 0.f;
#pragma unroll
        for (int o = 0; o < 16; ++o) s += w0[h * 2048 + k * 16 + o] * av[h * 16 + o];
        mtg[m] = (_Float16)s;
    }
}

// ---------------- Layer-0 projection via MFMA (f16 in, f32 acc) ----------------
__device__ __forceinline__ v8h cvt8(float4 lo, float4 hi) {
    v8h r;
    r[0] = (_Float16)lo.x; r[1] = (_Float16)lo.y; r[2] = (_Float16)lo.z; r[3] = (_Float16)lo.w;
    r[4] = (_Float16)hi.x; r[5] = (_Float16)hi.y; r[6] = (_Float16)hi.z; r[7] = (_Float16)hi.w;
    return r;
}

__global__ __launch_bounds__(256) void gemm0_kernel(
    const float* __restrict__ stat, const float* __restrict__ dyn0,
    const float* __restrict__ dyn1, const float4* __restrict__ wt4g,
    const _Float16* __restrict__ mtg,
    __half* __restrict__ hp_half, float* __restrict__ s0, float* __restrict__ t0,
    int n_nodes)
{
    __shared__ char wt_s[32768];   // 128 rows (c) x 256B, XOR-swizzled
    int t = threadIdx.x;
    int nb = blockIdx.x * 64;

#pragma unroll
    for (int j = 0; j < 8; ++j) {
        int i = t + j * 256;
        int c = i >> 4;
        int dst = (i * 16) ^ ((c & 7) << 4);
        *reinterpret_cast<float4*>(wt_s + dst) = wt4g[i];
    }
    __syncthreads();

    int l = t & 63, w = t >> 6;
    int cl = l & 15, klo = l >> 4;
    int rowbase = w * 16;
    int rg = min(nb + rowbase + cl, n_nodes - 1);

    v8h a[4];
    {
        float4 lo, hi;
        lo = *reinterpret_cast<const float4*>(&dyn0[(size_t)rg * 32 + klo * 8]);
        hi = *reinterpret_cast<const float4*>(&dyn0[(size_t)rg * 32 + klo * 8 + 4]);
        a[0] = cvt8(lo, hi);
        lo = *reinterpret_cast<const float4*>(&dyn1[(size_t)rg * 32 + klo * 8]);
        hi = *reinterpret_cast<const float4*>(&dyn1[(size_t)rg * 32 + klo * 8 + 4]);
        a[1] = cvt8(lo, hi);
        lo = *reinterpret_cast<const float4*>(&stat[(size_t)rg * 64 + klo * 8]);
        hi = *reinterpret_cast<const float4*>(&stat[(size_t)rg * 64 + klo * 8 + 4]);
        a[2] = cvt8(lo, hi);
        lo = *reinterpret_cast<const float4*>(&stat[(size_t)rg * 64 + 32 + klo * 8]);
        hi = *reinterpret_cast<const float4*>(&stat[(size_t)rg * 64 + 32 + klo * 8 + 4]);
        a[3] = cvt8(lo, hi);
    }

    f32x4 sacc = {0.f, 0.f, 0.f, 0.f};
#pragma unroll
    for (int kk = 0; kk < 4; ++kk) {
        v8h b = *reinterpret_cast<const v8h*>(&mtg[(size_t)cl * 128 + kk * 32 + klo * 8]);
        sacc = __builtin_amdgcn_mfma_f32_16x16x32_f16(a[kk], b, sacc, 0, 0, 0);
    }

    f32x4 acc[8];
#pragma unroll
    for (int cb = 0; cb < 8; ++cb) {
        f32x4 c = {0.f, 0.f, 0.f, 0.f};
#pragma unroll
        for (int kk = 0; kk < 4; ++kk) {
            int cc = cb * 16 + cl;
            int byte = (cc * 256 + kk * 64 + klo * 16) ^ ((cl & 7) << 4);
            v8h b = *reinterpret_cast<const v8h*>(wt_s + byte);
            c = __builtin_amdgcn_mfma_f32_16x16x32_f16(a[kk], b, c, 0, 0, 0);
        }
        acc[cb] = c;
    }

#pragma unroll
    for (int r = 0; r < 4; ++r) {
        int node = nb + rowbase + klo * 4 + r;
        if (node < n_nodes) {
#pragma unroll
            for (int cb = 0; cb < 8; ++cb)
                hp_half[(size_t)node * 128 + cb * 16 + cl] = (__half)acc[cb][r];
            if (cl < 8) s0[node * 8 + cl]     = sacc[r];
            else        t0[node * 8 + cl - 8] = sacc[r];
        }
    }
}

// ---------------- Layer-0 aggregate: one WAVE per target node (round-17 body) ----
#define CH 64
__global__ __launch_bounds__(256) void node_accum0_kernel(
    const int* __restrict__ rowptr, const int* __restrict__ colsrc,
    const float* __restrict__ s0, const float* __restrict__ t0,
    const __half2* __restrict__ hp0h, const float* __restrict__ w1,
    const float* __restrict__ asrc1, const float* __restrict__ atrg1,
    float4* __restrict__ pk1, float* __restrict__ t1, int n_nodes)
{
    __shared__ int   se_s[4][CH];
    __shared__ float p_s[4][CH * 8];

    int w = threadIdx.x >> 6;
    int l = threadIdx.x & 63;
    int n = blockIdx.x * 4 + w;
    if (n >= n_nodes) return;

    int start = rowptr[n];
    int deg = rowptr[n + 1] - start;
    int hl = l & 7;
    int g  = l >> 5;
    int j  = l & 31;
    int hc2 = j >> 2;
    float tval = t0[n * 8 + hl];
    const float* pw = p_s[w];

    float a0 = 0.f, a1 = 0.f, a2 = 0.f, a3 = 0.f, dsum = 0.f;
    for (int chunk = 0; chunk < deg; chunk += CH) {
        int m = min(CH, deg - chunk);
        se_s[w][l] = (l < m) ? colsrc[start + chunk + l] : 0;
        __builtin_amdgcn_wave_barrier();
        int iters = (m + 7) >> 3;
        for (int r = 0; r < iters; ++r) {
            int e = r * 8 + (l >> 3);
            float p = 0.f;
            if (e < m) {
                int se = se_s[w][e];
                float x = s0[se * 8 + hl] + tval;
                p = __expf(lrelu02(x) - ESHIFT);
            }
            p_s[w][r * 64 + l] = p;
            dsum += p;
        }
        __builtin_amdgcn_wave_barrier();
        int e = 0;
        for (; e + 4 <= m; e += 4) {
            int sa = se_s[w][e + g];
            int sb = se_s[w][e + 2 + g];
            float2 ra = *reinterpret_cast<const float2*>(&hp0h[(size_t)sa * 64 + j * 2]);
            float2 rb = *reinterpret_cast<const float2*>(&hp0h[(size_t)sb * 64 + j * 2]);
            float pa = pw[(e + g) * 8 + hc2];
            float pb = pw[(e + 2 + g) * 8 + hc2];
            const __half2* ha = reinterpret_cast<const __half2*>(&ra);
            const __half2* hb = reinterpret_cast<const __half2*>(&rb);
            float2 fa0 = __half22float2(ha[0]), fa1 = __half22float2(ha[1]);
            float2 fb0 = __half22float2(hb[0]), fb1 = __half22float2(hb[1]);
            a0 += fa0.x * pa; a1 += fa0.y * pa; a2 += fa1.x * pa; a3 += fa1.y * pa;
            a0 += fb0.x * pb; a1 += fb0.y * pb; a2 += fb1.x * pb; a3 += fb1.y * pb;
        }
        for (; e < m; e += 2) {
            int ee = e + g;
            int se = se_s[w][ee];
            float2 ra = *reinterpret_cast<const float2*>(&hp0h[(size_t)se * 64 + j * 2]);
            float p = pw[ee * 8 + hc2];
            const __half2* ha = reinterpret_cast<const __half2*>(&ra);
            float2 f0 = __half22float2(ha[0]), f1 = __half22float2(ha[1]);
            a0 += f0.x * p; a1 += f0.y * p; a2 += f1.x * p; a3 += f1.y * p;
        }
        __builtin_amdgcn_wave_barrier();
    }

    a0 += __shfl_xor(a0, 32);
    a1 += __shfl_xor(a1, 32);
    a2 += __shfl_xor(a2, 32);
    a3 += __shfl_xor(a3, 32);

    dsum += __shfl_xor(dsum, 8);
    dsum += __shfl_xor(dsum, 16);
    dsum += __shfl_xor(dsum, 32);
    float denom = __shfl(dsum, hc2);
    float inv = 1.f / (denom + 1e-16f);
    float v0 = a0 * inv; v0 = v0 > 0.f ? v0 : expm1f(v0);
    float v1 = a1 * inv; v1 = v1 > 0.f ? v1 : expm1f(v1);
    float v2 = a2 * inv; v2 = v2 > 0.f ? v2 : expm1f(v2);
    float v3 = a3 * inv; v3 = v3 > 0.f ? v3 : expm1f(v3);

    float4 wv0 = *reinterpret_cast<const float4*>(&w1[j * 8]);
    float4 wv1 = *reinterpret_cast<const float4*>(&w1[j * 8 + 4]);
    float r0 = v0 * wv0.x + v1 * wv0.z + v2 * wv1.x + v3 * wv1.z;
    float r1 = v0 * wv0.y + v1 * wv0.w + v2 * wv1.y + v3 * wv1.w;
#pragma unroll
    for (int off = 16; off > 0; off >>= 1) {
        r0 += __shfl_down(r0, off);
        r1 += __shfl_down(r1, off);
    }
    if (l == 0) {
        float s1v = r0 * asrc1[0] + r1 * asrc1[1];
        float t1v = r0 * atrg1[0] + r1 * atrg1[1];
        float4 pk; pk.x = r0; pk.y = r1; pk.z = s1v; pk.w = 0.f;
        pk1[n] = pk;
        t1[n] = t1v;
    }
}

// ---------------- Layer-1 aggregate: 16 LANES per node (mean deg = 16) ----------
__global__ __launch_bounds__(256) void node_accum1_kernel(
    const int* __restrict__ rowptr, const int* __restrict__ colsrc,
    const float4* __restrict__ pk1, const float* __restrict__ t1,
    float* __restrict__ out, int n_nodes)
{
    int lane = threadIdx.x & 15;
    int n = blockIdx.x * 16 + (threadIdx.x >> 4);
    if (n >= n_nodes) return;
    int start = rowptr[n], deg = rowptr[n + 1] - start;
    float tn = t1[n];
    float d = 0.f, a0 = 0.f, a1 = 0.f;
    for (int i = lane; i < deg; i += 16) {
        int se = colsrc[start + i];
        float4 q = pk1[se];
        float p = __expf(lrelu02(q.z + tn) - ESHIFT);
        d += p;
        a0 += p * q.x;
        a1 += p * q.y;
    }
#pragma unroll
    for (int off = 8; off > 0; off >>= 1) {
        d  += __shfl_xor(d, off);
        a0 += __shfl_xor(a0, off);
        a1 += __shfl_xor(a1, off);
    }
    if (lane == 0) {
        float inv = 1.f / (d + 1e-16f);
        float x0 = a0 * inv, x1 = a1 * inv;
        float m = fmaxf(x0, x1);
        float lse = m + logf(__expf(x0 - m) + __expf(x1 - m));
        out[n * 2 + 0] = x0 - lse;
        out[n * 2 + 1] = x1 - lse;
    }
}

extern "C" void kernel_launch(void* const* d_in, const int* in_sizes, int n_in,
                              void* d_out, int out_size, void* d_ws, size_t ws_size,
                              hipStream_t stream) {
    const float* stat  = (const float*)d_in[0];
    const float* dyn0  = (const float*)d_in[1];
    const float* dyn1  = (const float*)d_in[2];
    const int*   src   = (const int*)d_in[3];
    const int*   trg   = (const int*)d_in[4];
    const float* w0    = (const float*)d_in[5];
    const float* asrc0 = (const float*)d_in[6];
    const float* atrg0 = (const float*)d_in[7];
    const float* w1    = (const float*)d_in[8];
    const float* asrc1 = (const float*)d_in[9];
    const float* atrg1 = (const float*)d_in[10];
    float* out = (float*)d_out;

    const int N = in_sizes[0] / 64;   // 50000
    const int E = in_sizes[3];        // 800000
    const int NBK = (N + 255) >> 8;   // 196 buckets of 256 nodes
    const int CHUNK = (E + NCHUNK - 1) / NCHUNK;
    const int NTB = (N + 63) >> 6;    // 782 gemm0 blocks (64 nodes each)

    // ---- workspace layout ----
    float* ws = (float*)d_ws;
    size_t off = 0;
    __half2* hp0h = (__half2*)(ws + off);
    int2*    stage = (int2*)(ws + off);
    off += (size_t)N * 64;
    float* s0  = ws + off; off += (size_t)N * 8;
    float* t0  = ws + off; off += (size_t)N * 8;
    float4* pk1 = (float4*)(ws + off); off += (size_t)N * 4;
    float* t1  = ws + off; off += (size_t)N;
    _Float16* wt  = (_Float16*)(ws + off); off += 8192;   // 32KB fp16 W^T [c][k]
    _Float16* mtg = (_Float16*)(ws + off); off += 1024;   // 4KB fp16 Bs^T [j][k]
    off = (off + 3) & ~(size_t)3;
    int* iws      = (int*)(ws + off);
    int* rowptr   = iws;                        // NBK*256 + 1
    int* colsrc   = rowptr + NBK * 256 + 1;     // E
    int* H        = colsrc + E;                 // NCHUNK*NBK
    int* basearr  = H + NCHUNK * NBK;           // NCHUNK*NBK
    int* bktstart = basearr + NCHUNK * NBK;     // NBK+1

    // ---- CSR build (tile counting sort, no global atomics) ----
    sort_hist_kernel<<<NCHUNK, 1024, 0, stream>>>(trg, H, E, NBK, CHUNK);
    sort_scan_kernel<<<1, 256, 0, stream>>>(H, basearr, bktstart, rowptr, NBK, E);
    sort_scatter_kernel<<<NCHUNK, 1024, 0, stream>>>(src, trg, basearr, stage, E, NBK, CHUNK);
    sort_finalize_kernel<<<NBK, 256, 0, stream>>>(stage, bktstart, rowptr, colsrc, NBK);

    // ---- W pre-pack (fp16 W^T + folded score matrix), then MFMA projection ----
    wconv_kernel<<<72, 256, 0, stream>>>(w0, asrc0, atrg0, wt, mtg);
    gemm0_kernel<<<NTB, 256, 0, stream>>>(
        stat, dyn0, dyn1, (const float4*)wt, mtg, (__half*)hp0h, s0, t0, N);

    // ---- layer 0 aggregate + ELU + W1 + layer-1 scores (wave per node) ----
    node_accum0_kernel<<<(N + 3) / 4, 256, 0, stream>>>(
        rowptr, colsrc, s0, t0, hp0h, w1, asrc1, atrg1, pk1, t1, N);

    // ---- layer 1 aggregate + mean + log_softmax (16 lanes/node) ----
    node_accum1_kernel<<<(N + 15) / 16, 256, 0, stream>>>(
        rowptr, colsrc, pk1, t1, out, N);
}

// Round 21
// 92.286 us; speedup vs baseline: 1.2622x; 1.1169x over previous
//
#include <hip/hip_runtime.h>
#include <hip/hip_fp16.h>
#include <math.h>

__device__ __forceinline__ float lrelu02(float x) { return x > 0.f ? x : 0.2f * x; }

typedef _Float16 v8h __attribute__((ext_vector_type(8)));
typedef float f32x4 __attribute__((ext_vector_type(4)));

#define ESHIFT 10.0f   // constant shift replacing global max (alpha is ratio-invariant)
#define NCHUNK 128     // sort chunks (blocks in P1/P3)

// ============ CSR build: tile counting sort, NO global atomics ============
__global__ __launch_bounds__(1024) void sort_hist_kernel(
    const int* __restrict__ trg, int* __restrict__ H, int E, int nbk, int chunk)
{
    __shared__ int hist[256];
    int c = blockIdx.x, t = threadIdx.x;
    if (t < 256) hist[t] = 0;
    __syncthreads();
    int e0 = c * chunk, e1 = min(e0 + chunk, E);
    for (int i = e0 + t; i < e1; i += 1024)
        atomicAdd(&hist[trg[i] >> 8], 1);
    __syncthreads();
    if (t < nbk) H[c * nbk + t] = hist[t];
}

// K2: block 0 = bucket scan; blocks 1..72 = W pre-pack (independent work)
__global__ __launch_bounds__(256) void scan_wconv_kernel(
    const int* __restrict__ H, int* __restrict__ base,
    int* __restrict__ bktstart, int* __restrict__ rowptr,
    int nbk, int E,
    const float* __restrict__ w0, const float* __restrict__ asrc0,
    const float* __restrict__ atrg0, _Float16* __restrict__ wt,
    _Float16* __restrict__ mtg)
{
    int t = threadIdx.x;
    if (blockIdx.x == 0) {
        __shared__ int sm[256];
        int hv[NCHUNK];
        int tot = 0;
        if (t < nbk) {
#pragma unroll
            for (int c = 0; c < NCHUNK; ++c) hv[c] = H[c * nbk + t];
#pragma unroll
            for (int c = 0; c < NCHUNK; ++c) tot += hv[c];
        }
        sm[t] = tot;
        __syncthreads();
        for (int off = 1; off < 256; off <<= 1) {
            int x = (t >= off) ? sm[t - off] : 0;
            __syncthreads();
            sm[t] += x;
            __syncthreads();
        }
        int excl = sm[t] - tot;
        if (t < nbk) {
            bktstart[t] = excl;
            int run = excl;
#pragma unroll
            for (int c = 0; c < NCHUNK; ++c) { base[c * nbk + t] = run; run += hv[c]; }
        }
        if (t == 0) { bktstart[nbk] = E; rowptr[nbk * 256] = E; }
    } else {
        int i = (blockIdx.x - 1) * 256 + t;
        if (i < 16384) {
            int c = i >> 7, k = i & 127;
            int h = c >> 4, o = c & 15;
            wt[i] = (_Float16)w0[h * 2048 + k * 16 + o];
        } else if (i < 16384 + 2048) {
            int m = i - 16384;
            int j = m >> 7, k = m & 127;
            int h = j & 7;
            const float* av = (j < 8) ? asrc0 : atrg0;
            float s = 0.f;
#pragma unroll
            for (int o = 0; o < 16; ++o) s += w0[h * 2048 + k * 16 + o] * av[h * 16 + o];
            mtg[m] = (_Float16)s;
        }
    }
}

__global__ __launch_bounds__(1024) void sort_scatter_kernel(
    const int* __restrict__ src, const int* __restrict__ trg,
    const int* __restrict__ base, int2* __restrict__ stage,
    int E, int nbk, int chunk)
{
    __shared__ int cur[256];
    int c = blockIdx.x, t = threadIdx.x;
    if (t < nbk) cur[t] = base[c * nbk + t];
    __syncthreads();
    int e0 = c * chunk, e1 = min(e0 + chunk, E);
    for (int i = e0 + t; i < e1; i += 1024) {
        int tg = trg[i];
        int pos = atomicAdd(&cur[tg >> 8], 1);
        stage[pos] = make_int2(src[i], tg);
    }
}

__device__ __forceinline__ v8h cvt8(float4 lo, float4 hi) {
    v8h r;
    r[0] = (_Float16)lo.x; r[1] = (_Float16)lo.y; r[2] = (_Float16)lo.z; r[3] = (_Float16)lo.w;
    r[4] = (_Float16)hi.x; r[5] = (_Float16)hi.y; r[6] = (_Float16)hi.z; r[7] = (_Float16)hi.w;
    return r;
}

// K4: blocks 0..nbk-1 = finalize (bucket CSR); blocks nbk.. = MFMA gemm0.
// stage now has a DEDICATED region (no alias with hp) so the two halves are
// race-free.
__global__ __launch_bounds__(256) void finalize_gemm0_kernel(
    const int2* __restrict__ stage, const int* __restrict__ bktstart,
    int* __restrict__ rowptr, int* __restrict__ colsrc, int nbk,
    const float* __restrict__ stat, const float* __restrict__ dyn0,
    const float* __restrict__ dyn1, const float4* __restrict__ wt4g,
    const _Float16* __restrict__ mtg,
    __half* __restrict__ hp_half, float* __restrict__ s0, float* __restrict__ t0,
    int n_nodes)
{
    __shared__ char smem[32768];
    int t = threadIdx.x;
    if ((int)blockIdx.x < nbk) {
        int* hist = (int*)smem;
        int* sm   = hist + 256;
        int* cur  = sm + 256;
        int b = blockIdx.x;
        int s0i = bktstart[b], cnt = bktstart[b + 1] - s0i;
        hist[t] = 0;
        __syncthreads();
        for (int i = t; i < cnt; i += 256)
            atomicAdd(&hist[stage[s0i + i].y & 255], 1);
        __syncthreads();
        int h = hist[t];
        sm[t] = h;
        __syncthreads();
        for (int off = 1; off < 256; off <<= 1) {
            int x = (t >= off) ? sm[t - off] : 0;
            __syncthreads();
            sm[t] += x;
            __syncthreads();
        }
        int excl = sm[t] - h;
        cur[t] = s0i + excl;
        rowptr[b * 256 + t] = s0i + excl;
        __syncthreads();
        for (int i = t; i < cnt; i += 256) {
            int2 p = stage[s0i + i];
            int pos = atomicAdd(&cur[p.y & 255], 1);
            colsrc[pos] = p.x;
        }
    } else {
        char* wt_s = smem;   // 128 rows (c) x 256B, XOR-swizzled
        int nb = (blockIdx.x - nbk) * 64;

#pragma unroll
        for (int j = 0; j < 8; ++j) {
            int i = t + j * 256;
            int c = i >> 4;
            int dst = (i * 16) ^ ((c & 7) << 4);
            *reinterpret_cast<float4*>(wt_s + dst) = wt4g[i];
        }
        __syncthreads();

        int l = t & 63, w = t >> 6;
        int cl = l & 15, klo = l >> 4;
        int rowbase = w * 16;
        int rg = min(nb + rowbase + cl, n_nodes - 1);

        v8h a[4];
        {
            float4 lo, hi;
            lo = *reinterpret_cast<const float4*>(&dyn0[(size_t)rg * 32 + klo * 8]);
            hi = *reinterpret_cast<const float4*>(&dyn0[(size_t)rg * 32 + klo * 8 + 4]);
            a[0] = cvt8(lo, hi);
            lo = *reinterpret_cast<const float4*>(&dyn1[(size_t)rg * 32 + klo * 8]);
            hi = *reinterpret_cast<const float4*>(&dyn1[(size_t)rg * 32 + klo * 8 + 4]);
            a[1] = cvt8(lo, hi);
            lo = *reinterpret_cast<const float4*>(&stat[(size_t)rg * 64 + klo * 8]);
            hi = *reinterpret_cast<const float4*>(&stat[(size_t)rg * 64 + klo * 8 + 4]);
            a[2] = cvt8(lo, hi);
            lo = *reinterpret_cast<const float4*>(&stat[(size_t)rg * 64 + 32 + klo * 8]);
            hi = *reinterpret_cast<const float4*>(&stat[(size_t)rg * 64 + 32 + klo * 8 + 4]);
            a[3] = cvt8(lo, hi);
        }

        f32x4 sacc = {0.f, 0.f, 0.f, 0.f};
#pragma unroll
        for (int kk = 0; kk < 4; ++kk) {
            v8h b = *reinterpret_cast<const v8h*>(&mtg[(size_t)cl * 128 + kk * 32 + klo * 8]);
            sacc = __builtin_amdgcn_mfma_f32_16x16x32_f16(a[kk], b, sacc, 0, 0, 0);
        }

        f32x4 acc[8];
#pragma unroll
        for (int cb = 0; cb < 8; ++cb) {
            f32x4 c = {0.f, 0.f, 0.f, 0.f};
#pragma unroll
            for (int kk = 0; kk < 4; ++kk) {
                int cc = cb * 16 + cl;
                int byte = (cc * 256 + kk * 64 + klo * 16) ^ ((cl & 7) << 4);
                v8h b = *reinterpret_cast<const v8h*>(wt_s + byte);
                c = __builtin_amdgcn_mfma_f32_16x16x32_f16(a[kk], b, c, 0, 0, 0);
            }
            acc[cb] = c;
        }

#pragma unroll
        for (int r = 0; r < 4; ++r) {
            int node = nb + rowbase + klo * 4 + r;
            if (node < n_nodes) {
#pragma unroll
                for (int cb = 0; cb < 8; ++cb)
                    hp_half[(size_t)node * 128 + cb * 16 + cl] = (__half)acc[cb][r];
                if (cl < 8) s0[node * 8 + cl]     = sacc[r];
                else        t0[node * 8 + cl - 8] = sacc[r];
            }
        }
    }
}

// ---------------- Layer-0 aggregate: one WAVE per target node ----------------
#define CH 64
__global__ __launch_bounds__(256) void node_accum0_kernel(
    const int* __restrict__ rowptr, const int* __restrict__ colsrc,
    const float* __restrict__ s0, const float* __restrict__ t0,
    const __half2* __restrict__ hp0h, const float* __restrict__ w1,
    const float* __restrict__ asrc1, const float* __restrict__ atrg1,
    float4* __restrict__ pk1, float* __restrict__ t1, int n_nodes)
{
    __shared__ int   se_s[4][CH];
    __shared__ float p_s[4][CH * 8];

    int w = threadIdx.x >> 6;
    int l = threadIdx.x & 63;
    int n = blockIdx.x * 4 + w;
    if (n >= n_nodes) return;

    int start = rowptr[n];
    int deg = rowptr[n + 1] - start;
    int hl = l & 7;
    int g  = l >> 5;
    int j  = l & 31;
    int hc2 = j >> 2;
    float tval = t0[n * 8 + hl];
    const float* pw = p_s[w];

    float a0 = 0.f, a1 = 0.f, a2 = 0.f, a3 = 0.f, dsum = 0.f;
    for (int chunk = 0; chunk < deg; chunk += CH) {
        int m = min(CH, deg - chunk);
        se_s[w][l] = (l < m) ? colsrc[start + chunk + l] : 0;
        __builtin_amdgcn_wave_barrier();
        int iters = (m + 7) >> 3;
        for (int r = 0; r < iters; ++r) {
            int e = r * 8 + (l >> 3);
            float p = 0.f;
            if (e < m) {
                int se = se_s[w][e];
                float x = s0[se * 8 + hl] + tval;
                p = __expf(lrelu02(x) - ESHIFT);
            }
            p_s[w][r * 64 + l] = p;
            dsum += p;
        }
        __builtin_amdgcn_wave_barrier();
        int e = 0;
        for (; e + 4 <= m; e += 4) {
            int sa = se_s[w][e + g];
            int sb = se_s[w][e + 2 + g];
            float2 ra = *reinterpret_cast<const float2*>(&hp0h[(size_t)sa * 64 + j * 2]);
            float2 rb = *reinterpret_cast<const float2*>(&hp0h[(size_t)sb * 64 + j * 2]);
            float pa = pw[(e + g) * 8 + hc2];
            float pb = pw[(e + 2 + g) * 8 + hc2];
            const __half2* ha = reinterpret_cast<const __half2*>(&ra);
            const __half2* hb = reinterpret_cast<const __half2*>(&rb);
            float2 fa0 = __half22float2(ha[0]), fa1 = __half22float2(ha[1]);
            float2 fb0 = __half22float2(hb[0]), fb1 = __half22float2(hb[1]);
            a0 += fa0.x * pa; a1 += fa0.y * pa; a2 += fa1.x * pa; a3 += fa1.y * pa;
            a0 += fb0.x * pb; a1 += fb0.y * pb; a2 += fb1.x * pb; a3 += fb1.y * pb;
        }
        for (; e < m; e += 2) {
            int ee = e + g;
            int se = se_s[w][ee];
            float2 ra = *reinterpret_cast<const float2*>(&hp0h[(size_t)se * 64 + j * 2]);
            float p = pw[ee * 8 + hc2];
            const __half2* ha = reinterpret_cast<const __half2*>(&ra);
            float2 f0 = __half22float2(ha[0]), f1 = __half22float2(ha[1]);
            a0 += f0.x * p; a1 += f0.y * p; a2 += f1.x * p; a3 += f1.y * p;
        }
        __builtin_amdgcn_wave_barrier();
    }

    a0 += __shfl_xor(a0, 32);
    a1 += __shfl_xor(a1, 32);
    a2 += __shfl_xor(a2, 32);
    a3 += __shfl_xor(a3, 32);

    dsum += __shfl_xor(dsum, 8);
    dsum += __shfl_xor(dsum, 16);
    dsum += __shfl_xor(dsum, 32);
    float denom = __shfl(dsum, hc2);
    float inv = 1.f / (denom + 1e-16f);
    float v0 = a0 * inv; v0 = v0 > 0.f ? v0 : expm1f(v0);
    float v1 = a1 * inv; v1 = v1 > 0.f ? v1 : expm1f(v1);
    float v2 = a2 * inv; v2 = v2 > 0.f ? v2 : expm1f(v2);
    float v3 = a3 * inv; v3 = v3 > 0.f ? v3 : expm1f(v3);

    float4 wv0 = *reinterpret_cast<const float4*>(&w1[j * 8]);
    float4 wv1 = *reinterpret_cast<const float4*>(&w1[j * 8 + 4]);
    float r0 = v0 * wv0.x + v1 * wv0.z + v2 * wv1.x + v3 * wv1.z;
    float r1 = v0 * wv0.y + v1 * wv0.w + v2 * wv1.y + v3 * wv1.w;
#pragma unroll
    for (int off = 16; off > 0; off >>= 1) {
        r0 += __shfl_down(r0, off);
        r1 += __shfl_down(r1, off);
    }
    if (l == 0) {
        float s1v = r0 * asrc1[0] + r1 * asrc1[1];
        float t1v = r0 * atrg1[0] + r1 * atrg1[1];
        float4 pk; pk.x = r0; pk.y = r1; pk.z = s1v; pk.w = 0.f;
        pk1[n] = pk;
        t1[n] = t1v;
    }
}

// ---------------- Layer-1 aggregate: 16 LANES per node (mean deg = 16) ----------
__global__ __launch_bounds__(256) void node_accum1_kernel(
    const int* __restrict__ rowptr, const int* __restrict__ colsrc,
    const float4* __restrict__ pk1, const float* __restrict__ t1,
    float* __restrict__ out, int n_nodes)
{
    int lane = threadIdx.x & 15;
    int n = blockIdx.x * 16 + (threadIdx.x >> 4);
    if (n >= n_nodes) return;
    int start = rowptr[n], deg = rowptr[n + 1] - start;
    float tn = t1[n];
    float d = 0.f, a0 = 0.f, a1 = 0.f;
    for (int i = lane; i < deg; i += 16) {
        int se = colsrc[start + i];
        float4 q = pk1[se];
        float p = __expf(lrelu02(q.z + tn) - ESHIFT);
        d += p;
        a0 += p * q.x;
        a1 += p * q.y;
    }
#pragma unroll
    for (int off = 8; off > 0; off >>= 1) {
        d  += __shfl_xor(d, off);
        a0 += __shfl_xor(a0, off);
        a1 += __shfl_xor(a1, off);
    }
    if (lane == 0) {
        float inv = 1.f / (d + 1e-16f);
        float x0 = a0 * inv, x1 = a1 * inv;
        float m = fmaxf(x0, x1);
        float lse = m + logf(__expf(x0 - m) + __expf(x1 - m));
        out[n * 2 + 0] = x0 - lse;
        out[n * 2 + 1] = x1 - lse;
    }
}

extern "C" void kernel_launch(void* const* d_in, const int* in_sizes, int n_in,
                              void* d_out, int out_size, void* d_ws, size_t ws_size,
                              hipStream_t stream) {
    const float* stat  = (const float*)d_in[0];
    const float* dyn0  = (const float*)d_in[1];
    const float* dyn1  = (const float*)d_in[2];
    const int*   src   = (const int*)d_in[3];
    const int*   trg   = (const int*)d_in[4];
    const float* w0    = (const float*)d_in[5];
    const float* asrc0 = (const float*)d_in[6];
    const float* atrg0 = (const float*)d_in[7];
    const float* w1    = (const float*)d_in[8];
    const float* asrc1 = (const float*)d_in[9];
    const float* atrg1 = (const float*)d_in[10];
    float* out = (float*)d_out;

    const int N = in_sizes[0] / 64;   // 50000
    const int E = in_sizes[3];        // 800000
    const int NBK = (N + 255) >> 8;   // 196 buckets of 256 nodes
    const int CHUNK = (E + NCHUNK - 1) / NCHUNK;
    const int NTB = (N + 63) >> 6;    // 782 gemm0 tiles (64 nodes each)

    // ---- workspace layout (stage now has a DEDICATED region; ~27MB total,
    //      round-1 layout used ~57MB of d_ws successfully) ----
    float* ws = (float*)d_ws;
    size_t off = 0;
    __half2* hp0h = (__half2*)(ws + off); off += (size_t)N * 64;   // 12.8MB
    int2*    stage = (int2*)(ws + off);   off += (size_t)E * 2;    // 6.4MB dedicated
    float* s0  = ws + off; off += (size_t)N * 8;
    float* t0  = ws + off; off += (size_t)N * 8;
    float4* pk1 = (float4*)(ws + off); off += (size_t)N * 4;
    float* t1  = ws + off; off += (size_t)N;
    _Float16* wt  = (_Float16*)(ws + off); off += 8192;   // 32KB fp16 W^T [c][k]
    _Float16* mtg = (_Float16*)(ws + off); off += 1024;   // 4KB fp16 Bs^T [j][k]
    off = (off + 3) & ~(size_t)3;
    int* iws      = (int*)(ws + off);
    int* rowptr   = iws;                        // NBK*256 + 1
    int* colsrc   = rowptr + NBK * 256 + 1;     // E
    int* H        = colsrc + E;                 // NCHUNK*NBK
    int* basearr  = H + NCHUNK * NBK;           // NCHUNK*NBK
    int* bktstart = basearr + NCHUNK * NBK;     // NBK+1

    // K1: per-chunk bucket histogram
    sort_hist_kernel<<<NCHUNK, 1024, 0, stream>>>(trg, H, E, NBK, CHUNK);
    // K2: bucket scan (block 0) || W pre-pack (blocks 1..72)
    scan_wconv_kernel<<<73, 256, 0, stream>>>(
        H, basearr, bktstart, rowptr, NBK, E, w0, asrc0, atrg0, wt, mtg);
    // K3: bucket-major pair scatter
    sort_scatter_kernel<<<NCHUNK, 1024, 0, stream>>>(src, trg, basearr, stage, E, NBK, CHUNK);
    // K4: per-bucket CSR finalize (blocks 0..NBK-1) || MFMA gemm0 (blocks NBK..)
    finalize_gemm0_kernel<<<NBK + NTB, 256, 0, stream>>>(
        stage, bktstart, rowptr, colsrc, NBK,
        stat, dyn0, dyn1, (const float4*)wt, mtg, (__half*)hp0h, s0, t0, N);
    // K5: layer-0 aggregate + ELU + W1 + layer-1 scores
    node_accum0_kernel<<<(N + 3) / 4, 256, 0, stream>>>(
        rowptr, colsrc, s0, t0, hp0h, w1, asrc1, atrg1, pk1, t1, N);
    // K6: layer-1 aggregate + mean + log_softmax
    node_accum1_kernel<<<(N + 15) / 16, 256, 0, stream>>>(
        rowptr, colsrc, pk1, t1, out, N);
}

// Round 22
// 87.662 us; speedup vs baseline: 1.3288x; 1.0528x over previous
//
#include <hip/hip_runtime.h>
#include <hip/hip_fp16.h>
#include <math.h>

__device__ __forceinline__ float lrelu02(float x) { return x > 0.f ? x : 0.2f * x; }

typedef _Float16 v8h __attribute__((ext_vector_type(8)));
typedef float f32x4 __attribute__((ext_vector_type(4)));
typedef float f32x2 __attribute__((ext_vector_type(2)));

#define ESHIFT 10.0f   // constant shift replacing global max (alpha is ratio-invariant)
#define NCHUNK 128     // sort chunks (blocks in P1/P3)

// ============ CSR build: tile counting sort, NO global atomics ============
__global__ __launch_bounds__(1024) void sort_hist_kernel(
    const int* __restrict__ trg, int* __restrict__ H, int E, int nbk, int chunk)
{
    __shared__ int hist[256];
    int c = blockIdx.x, t = threadIdx.x;
    if (t < 256) hist[t] = 0;
    __syncthreads();
    int e0 = c * chunk, e1 = min(e0 + chunk, E);
    for (int i = e0 + t; i < e1; i += 1024)
        atomicAdd(&hist[trg[i] >> 8], 1);
    __syncthreads();
    if (t < nbk) H[c * nbk + t] = hist[t];
}

// K2: block 0 = bucket scan; blocks 1..72 = W pre-pack (independent work)
__global__ __launch_bounds__(256) void scan_wconv_kernel(
    const int* __restrict__ H, int* __restrict__ base,
    int* __restrict__ bktstart, int* __restrict__ rowptr,
    int nbk, int E,
    const float* __restrict__ w0, const float* __restrict__ asrc0,
    const float* __restrict__ atrg0, _Float16* __restrict__ wt,
    _Float16* __restrict__ mtg)
{
    int t = threadIdx.x;
    if (blockIdx.x == 0) {
        __shared__ int sm[256];
        int hv[NCHUNK];
        int tot = 0;
        if (t < nbk) {
#pragma unroll
            for (int c = 0; c < NCHUNK; ++c) hv[c] = H[c * nbk + t];
#pragma unroll
            for (int c = 0; c < NCHUNK; ++c) tot += hv[c];
        }
        sm[t] = tot;
        __syncthreads();
        for (int off = 1; off < 256; off <<= 1) {
            int x = (t >= off) ? sm[t - off] : 0;
            __syncthreads();
            sm[t] += x;
            __syncthreads();
        }
        int excl = sm[t] - tot;
        if (t < nbk) {
            bktstart[t] = excl;
            int run = excl;
#pragma unroll
            for (int c = 0; c < NCHUNK; ++c) { base[c * nbk + t] = run; run += hv[c]; }
        }
        if (t == 0) { bktstart[nbk] = E; rowptr[nbk * 256] = E; }
    } else {
        int i = (blockIdx.x - 1) * 256 + t;
        if (i < 16384) {
            int c = i >> 7, k = i & 127;
            int h = c >> 4, o = c & 15;
            wt[i] = (_Float16)w0[h * 2048 + k * 16 + o];
        } else if (i < 16384 + 2048) {
            int m = i - 16384;
            int j = m >> 7, k = m & 127;
            int h = j & 7;
            const float* av = (j < 8) ? asrc0 : atrg0;
            float s = 0.f;
#pragma unroll
            for (int o = 0; o < 16; ++o) s += w0[h * 2048 + k * 16 + o] * av[h * 16 + o];
            mtg[m] = (_Float16)s;
        }
    }
}

// K3: scatter packed (src | (trg&255)<<16) bucket-major via LDS cursors
__global__ __launch_bounds__(1024) void sort_scatter_kernel(
    const int* __restrict__ src, const int* __restrict__ trg,
    const int* __restrict__ base, unsigned int* __restrict__ stage,
    int E, int nbk, int chunk)
{
    __shared__ int cur[256];
    int c = blockIdx.x, t = threadIdx.x;
    if (t < nbk) cur[t] = base[c * nbk + t];
    __syncthreads();
    int e0 = c * chunk, e1 = min(e0 + chunk, E);
    for (int i = e0 + t; i < e1; i += 1024) {
        int tg = trg[i];
        int pos = atomicAdd(&cur[tg >> 8], 1);
        stage[pos] = (unsigned int)src[i] | ((unsigned int)(tg & 255) << 16);
    }
}

__device__ __forceinline__ v8h cvt8(float4 lo, float4 hi) {
    v8h r;
    r[0] = (_Float16)lo.x; r[1] = (_Float16)lo.y; r[2] = (_Float16)lo.z; r[3] = (_Float16)lo.w;
    r[4] = (_Float16)hi.x; r[5] = (_Float16)hi.y; r[6] = (_Float16)hi.z; r[7] = (_Float16)hi.w;
    return r;
}

// K4: blocks 0..nbk-1 = finalize (bucket CSR); blocks nbk.. = MFMA gemm0.
__global__ __launch_bounds__(256) void finalize_gemm0_kernel(
    const unsigned int* __restrict__ stage, const int* __restrict__ bktstart,
    int* __restrict__ rowptr, int* __restrict__ colsrc, int nbk,
    const float* __restrict__ stat, const float* __restrict__ dyn0,
    const float* __restrict__ dyn1, const float4* __restrict__ wt4g,
    const _Float16* __restrict__ mtg,
    unsigned char* __restrict__ hp8, float* __restrict__ s0, float* __restrict__ t0,
    int n_nodes)
{
    __shared__ char smem[32768];
    int t = threadIdx.x;
    if ((int)blockIdx.x < nbk) {
        int* hist = (int*)smem;
        int* sm   = hist + 256;
        int* cur  = sm + 256;
        int b = blockIdx.x;
        int s0i = bktstart[b], cnt = bktstart[b + 1] - s0i;
        hist[t] = 0;
        __syncthreads();
        for (int i = t; i < cnt; i += 256)
            atomicAdd(&hist[stage[s0i + i] >> 16], 1);
        __syncthreads();
        int h = hist[t];
        sm[t] = h;
        __syncthreads();
        for (int off = 1; off < 256; off <<= 1) {
            int x = (t >= off) ? sm[t - off] : 0;
            __syncthreads();
            sm[t] += x;
            __syncthreads();
        }
        int excl = sm[t] - h;
        cur[t] = s0i + excl;
        rowptr[b * 256 + t] = s0i + excl;
        __syncthreads();
        for (int i = t; i < cnt; i += 256) {
            unsigned int p = stage[s0i + i];
            int pos = atomicAdd(&cur[p >> 16], 1);
            colsrc[pos] = (int)(p & 0xFFFFu);
        }
    } else {
        char* wt_s = smem;   // 128 rows (c) x 256B, XOR-swizzled
        int nb = (blockIdx.x - nbk) * 64;

#pragma unroll
        for (int j = 0; j < 8; ++j) {
            int i = t + j * 256;
            int c = i >> 4;
            int dst = (i * 16) ^ ((c & 7) << 4);
            *reinterpret_cast<float4*>(wt_s + dst) = wt4g[i];
        }
        __syncthreads();

        int l = t & 63, w = t >> 6;
        int cl = l & 15, klo = l >> 4;
        int rowbase = w * 16;
        int rg = min(nb + rowbase + cl, n_nodes - 1);

        v8h a[4];
        {
            float4 lo, hi;
            lo = *reinterpret_cast<const float4*>(&dyn0[(size_t)rg * 32 + klo * 8]);
            hi = *reinterpret_cast<const float4*>(&dyn0[(size_t)rg * 32 + klo * 8 + 4]);
            a[0] = cvt8(lo, hi);
            lo = *reinterpret_cast<const float4*>(&dyn1[(size_t)rg * 32 + klo * 8]);
            hi = *reinterpret_cast<const float4*>(&dyn1[(size_t)rg * 32 + klo * 8 + 4]);
            a[1] = cvt8(lo, hi);
            lo = *reinterpret_cast<const float4*>(&stat[(size_t)rg * 64 + klo * 8]);
            hi = *reinterpret_cast<const float4*>(&stat[(size_t)rg * 64 + klo * 8 + 4]);
            a[2] = cvt8(lo, hi);
            lo = *reinterpret_cast<const float4*>(&stat[(size_t)rg * 64 + 32 + klo * 8]);
            hi = *reinterpret_cast<const float4*>(&stat[(size_t)rg * 64 + 32 + klo * 8 + 4]);
            a[3] = cvt8(lo, hi);
        }

        f32x4 sacc = {0.f, 0.f, 0.f, 0.f};
#pragma unroll
        for (int kk = 0; kk < 4; ++kk) {
            v8h b = *reinterpret_cast<const v8h*>(&mtg[(size_t)cl * 128 + kk * 32 + klo * 8]);
            sacc = __builtin_amdgcn_mfma_f32_16x16x32_f16(a[kk], b, sacc, 0, 0, 0);
        }

        f32x4 acc[8];
#pragma unroll
        for (int cb = 0; cb < 8; ++cb) {
            f32x4 c = {0.f, 0.f, 0.f, 0.f};
#pragma unroll
            for (int kk = 0; kk < 4; ++kk) {
                int cc = cb * 16 + cl;
                int byte = (cc * 256 + kk * 64 + klo * 16) ^ ((cl & 7) << 4);
                v8h b = *reinterpret_cast<const v8h*>(wt_s + byte);
                c = __builtin_amdgcn_mfma_f32_16x16x32_f16(a[kk], b, c, 0, 0, 0);
            }
            acc[cb] = c;
        }

#pragma unroll
        for (int r = 0; r < 4; ++r) {
            int node = nb + rowbase + klo * 4 + r;
            if (node < n_nodes) {
#pragma unroll
                for (int cb = 0; cb < 8; ++cb) {
                    int wv = __builtin_amdgcn_cvt_pk_fp8_f32(acc[cb][r], 0.f, 0, false);
                    hp8[(size_t)node * 128 + cb * 16 + cl] = (unsigned char)(wv & 0xFF);
                }
                if (cl < 8) s0[node * 8 + cl]     = sacc[r];
                else        t0[node * 8 + cl - 8] = sacc[r];
            }
        }
    }
}

// ---------------- Layer-0 aggregate: one WAVE per target node ----------------
// Lane j reads its 4 channels as ONE uint (fp8x4), HW-decoded via cvt_pk_f32_fp8.
#define CH 64
__global__ __launch_bounds__(256) void node_accum0_kernel(
    const int* __restrict__ rowptr, const int* __restrict__ colsrc,
    const float* __restrict__ s0, const float* __restrict__ t0,
    const unsigned char* __restrict__ hp8, const float* __restrict__ w1,
    const float* __restrict__ asrc1, const float* __restrict__ atrg1,
    float4* __restrict__ pk1, float* __restrict__ t1, int n_nodes)
{
    __shared__ int   se_s[4][CH];
    __shared__ float p_s[4][CH * 8];

    int w = threadIdx.x >> 6;
    int l = threadIdx.x & 63;
    int n = blockIdx.x * 4 + w;
    if (n >= n_nodes) return;

    int start = rowptr[n];
    int deg = rowptr[n + 1] - start;
    int hl = l & 7;
    int g  = l >> 5;
    int j  = l & 31;
    int hc2 = j >> 2;
    float tval = t0[n * 8 + hl];
    const float* pw = p_s[w];

    float a0 = 0.f, a1 = 0.f, a2 = 0.f, a3 = 0.f, dsum = 0.f;
    for (int chunk = 0; chunk < deg; chunk += CH) {
        int m = min(CH, deg - chunk);
        se_s[w][l] = (l < m) ? colsrc[start + chunk + l] : 0;
        __builtin_amdgcn_wave_barrier();
        int iters = (m + 7) >> 3;
        for (int r = 0; r < iters; ++r) {
            int e = r * 8 + (l >> 3);
            float p = 0.f;
            if (e < m) {
                int se = se_s[w][e];
                float x = s0[se * 8 + hl] + tval;
                p = __expf(lrelu02(x) - ESHIFT);
            }
            p_s[w][r * 64 + l] = p;
            dsum += p;
        }
        __builtin_amdgcn_wave_barrier();
        int e = 0;
        for (; e + 4 <= m; e += 4) {
            int sa = se_s[w][e + g];
            int sb = se_s[w][e + 2 + g];
            unsigned int va = *reinterpret_cast<const unsigned int*>(&hp8[(size_t)sa * 128 + j * 4]);
            unsigned int vb = *reinterpret_cast<const unsigned int*>(&hp8[(size_t)sb * 128 + j * 4]);
            float pa = pw[(e + g) * 8 + hc2];
            float pb = pw[(e + 2 + g) * 8 + hc2];
            f32x2 la = __builtin_amdgcn_cvt_pk_f32_fp8((int)va, false);
            f32x2 ha = __builtin_amdgcn_cvt_pk_f32_fp8((int)va, true);
            f32x2 lb = __builtin_amdgcn_cvt_pk_f32_fp8((int)vb, false);
            f32x2 hb = __builtin_amdgcn_cvt_pk_f32_fp8((int)vb, true);
            a0 += la[0] * pa; a1 += la[1] * pa; a2 += ha[0] * pa; a3 += ha[1] * pa;
            a0 += lb[0] * pb; a1 += lb[1] * pb; a2 += hb[0] * pb; a3 += hb[1] * pb;
        }
        for (; e < m; e += 2) {
            int ee = e + g;
            int se = se_s[w][ee];
            unsigned int v = *reinterpret_cast<const unsigned int*>(&hp8[(size_t)se * 128 + j * 4]);
            float p = pw[ee * 8 + hc2];
            f32x2 lo = __builtin_amdgcn_cvt_pk_f32_fp8((int)v, false);
            f32x2 hi = __builtin_amdgcn_cvt_pk_f32_fp8((int)v, true);
            a0 += lo[0] * p; a1 += lo[1] * p; a2 += hi[0] * p; a3 += hi[1] * p;
        }
        __builtin_amdgcn_wave_barrier();
    }

    a0 += __shfl_xor(a0, 32);
    a1 += __shfl_xor(a1, 32);
    a2 += __shfl_xor(a2, 32);
    a3 += __shfl_xor(a3, 32);

    dsum += __shfl_xor(dsum, 8);
    dsum += __shfl_xor(dsum, 16);
    dsum += __shfl_xor(dsum, 32);
    float denom = __shfl(dsum, hc2);
    float inv = 1.f / (denom + 1e-16f);
    float v0 = a0 * inv; v0 = v0 > 0.f ? v0 : expm1f(v0);
    float v1 = a1 * inv; v1 = v1 > 0.f ? v1 : expm1f(v1);
    float v2 = a2 * inv; v2 = v2 > 0.f ? v2 : expm1f(v2);
    float v3 = a3 * inv; v3 = v3 > 0.f ? v3 : expm1f(v3);

    float4 wv0 = *reinterpret_cast<const float4*>(&w1[j * 8]);
    float4 wv1 = *reinterpret_cast<const float4*>(&w1[j * 8 + 4]);
    float r0 = v0 * wv0.x + v1 * wv0.z + v2 * wv1.x + v3 * wv1.z;
    float r1 = v0 * wv0.y + v1 * wv0.w + v2 * wv1.y + v3 * wv1.w;
#pragma unroll
    for (int off = 16; off > 0; off >>= 1) {
        r0 += __shfl_down(r0, off);
        r1 += __shfl_down(r1, off);
    }
    if (l == 0) {
        float s1v = r0 * asrc1[0] + r1 * asrc1[1];
        float t1v = r0 * atrg1[0] + r1 * atrg1[1];
        float4 pk; pk.x = r0; pk.y = r1; pk.z = s1v; pk.w = 0.f;
        pk1[n] = pk;
        t1[n] = t1v;
    }
}

// ---------------- Layer-1 aggregate: 16 LANES per node (mean deg = 16) ----------
__global__ __launch_bounds__(256) void node_accum1_kernel(
    const int* __restrict__ rowptr, const int* __restrict__ colsrc,
    const float4* __restrict__ pk1, const float* __restrict__ t1,
    float* __restrict__ out, int n_nodes)
{
    int lane = threadIdx.x & 15;
    int n = blockIdx.x * 16 + (threadIdx.x >> 4);
    if (n >= n_nodes) return;
    int start = rowptr[n], deg = rowptr[n + 1] - start;
    float tn = t1[n];
    float d = 0.f, a0 = 0.f, a1 = 0.f;
    for (int i = lane; i < deg; i += 16) {
        int se = colsrc[start + i];
        float4 q = pk1[se];
        float p = __expf(lrelu02(q.z + tn) - ESHIFT);
        d += p;
        a0 += p * q.x;
        a1 += p * q.y;
    }
#pragma unroll
    for (int off = 8; off > 0; off >>= 1) {
        d  += __shfl_xor(d, off);
        a0 += __shfl_xor(a0, off);
        a1 += __shfl_xor(a1, off);
    }
    if (lane == 0) {
        float inv = 1.f / (d + 1e-16f);
        float x0 = a0 * inv, x1 = a1 * inv;
        float m = fmaxf(x0, x1);
        float lse = m + logf(__expf(x0 - m) + __expf(x1 - m));
        out[n * 2 + 0] = x0 - lse;
        out[n * 2 + 1] = x1 - lse;
    }
}

extern "C" void kernel_launch(void* const* d_in, const int* in_sizes, int n_in,
                              void* d_out, int out_size, void* d_ws, size_t ws_size,
                              hipStream_t stream) {
    const float* stat  = (const float*)d_in[0];
    const float* dyn0  = (const float*)d_in[1];
    const float* dyn1  = (const float*)d_in[2];
    const int*   src   = (const int*)d_in[3];
    const int*   trg   = (const int*)d_in[4];
    const float* w0    = (const float*)d_in[5];
    const float* asrc0 = (const float*)d_in[6];
    const float* atrg0 = (const float*)d_in[7];
    const float* w1    = (const float*)d_in[8];
    const float* asrc1 = (const float*)d_in[9];
    const float* atrg1 = (const float*)d_in[10];
    float* out = (float*)d_out;

    const int N = in_sizes[0] / 64;   // 50000 (src fits 16 bits)
    const int E = in_sizes[3];        // 800000
    const int NBK = (N + 255) >> 8;   // 196 buckets of 256 nodes
    const int CHUNK = (E + NCHUNK - 1) / NCHUNK;
    const int NTB = (N + 63) >> 6;    // 782 gemm0 tiles (64 nodes each)

    // ---- workspace layout (all regions dedicated, no aliasing) ----
    float* ws = (float*)d_ws;
    size_t off = 0;
    unsigned char* hp8 = (unsigned char*)(ws + off); off += (size_t)N * 32;  // 6.4MB fp8
    unsigned int* stage = (unsigned int*)(ws + off); off += (size_t)E;       // 3.2MB packed
    float* s0  = ws + off; off += (size_t)N * 8;
    float* t0  = ws + off; off += (size_t)N * 8;
    float4* pk1 = (float4*)(ws + off); off += (size_t)N * 4;
    float* t1  = ws + off; off += (size_t)N;
    _Float16* wt  = (_Float16*)(ws + off); off += 8192;   // 32KB fp16 W^T [c][k]
    _Float16* mtg = (_Float16*)(ws + off); off += 1024;   // 4KB fp16 Bs^T [j][k]
    off = (off + 3) & ~(size_t)3;
    int* iws      = (int*)(ws + off);
    int* rowptr   = iws;                        // NBK*256 + 1
    int* colsrc   = rowptr + NBK * 256 + 1;     // E
    int* H        = colsrc + E;                 // NCHUNK*NBK
    int* basearr  = H + NCHUNK * NBK;           // NCHUNK*NBK
    int* bktstart = basearr + NCHUNK * NBK;     // NBK+1

    // K1: per-chunk bucket histogram
    sort_hist_kernel<<<NCHUNK, 1024, 0, stream>>>(trg, H, E, NBK, CHUNK);
    // K2: bucket scan (block 0) || W pre-pack (blocks 1..72)
    scan_wconv_kernel<<<73, 256, 0, stream>>>(
        H, basearr, bktstart, rowptr, NBK, E, w0, asrc0, atrg0, wt, mtg);
    // K3: bucket-major packed-pair scatter
    sort_scatter_kernel<<<NCHUNK, 1024, 0, stream>>>(src, trg, basearr, stage, E, NBK, CHUNK);
    // K4: per-bucket CSR finalize (blocks 0..NBK-1) || MFMA gemm0 (blocks NBK..)
    finalize_gemm0_kernel<<<NBK + NTB, 256, 0, stream>>>(
        stage, bktstart, rowptr, colsrc, NBK,
        stat, dyn0, dyn1, (const float4*)wt, mtg, hp8, s0, t0, N);
    // K5: layer-0 aggregate + ELU + W1 + layer-1 scores
    node_accum0_kernel<<<(N + 3) / 4, 256, 0, stream>>>(
        rowptr, colsrc, s0, t0, hp8, w1, asrc1, atrg1, pk1, t1, N);
    // K6: layer-1 aggregate + mean + log_softmax
    node_accum1_kernel<<<(N + 15) / 16, 256, 0, stream>>>(
        rowptr, colsrc, pk1, t1, out, N);
}

// Round 23
// 87.330 us; speedup vs baseline: 1.3338x; 1.0038x over previous
//
#include <hip/hip_runtime.h>
#include <hip/hip_fp16.h>
#include <math.h>

__device__ __forceinline__ float lrelu02(float x) { return x > 0.f ? x : 0.2f * x; }

typedef _Float16 v8h __attribute__((ext_vector_type(8)));
typedef float f32x4 __attribute__((ext_vector_type(4)));
typedef float f32x2 __attribute__((ext_vector_type(2)));

#define ESHIFT 10.0f   // constant shift replacing global max (alpha is ratio-invariant)
#define NCHUNK 128     // sort chunks (blocks in P1/P3)

// ============ CSR build: tile counting sort, NO global atomics ============
__global__ __launch_bounds__(1024) void sort_hist_kernel(
    const int* __restrict__ trg, int* __restrict__ H, int E, int nbk, int chunk)
{
    __shared__ int hist[256];
    int c = blockIdx.x, t = threadIdx.x;
    if (t < 256) hist[t] = 0;
    __syncthreads();
    int e0 = c * chunk, e1 = min(e0 + chunk, E);
    for (int i = e0 + t; i < e1; i += 1024)
        atomicAdd(&hist[trg[i] >> 8], 1);
    __syncthreads();
    if (t < nbk) H[c * nbk + t] = hist[t];
}

// K2: block 0 = bucket scan; blocks 1..72 = W pre-pack (independent work)
__global__ __launch_bounds__(256) void scan_wconv_kernel(
    const int* __restrict__ H, int* __restrict__ base,
    int* __restrict__ bktstart, int* __restrict__ rowptr,
    int nbk, int E,
    const float* __restrict__ w0, const float* __restrict__ asrc0,
    const float* __restrict__ atrg0, _Float16* __restrict__ wt,
    _Float16* __restrict__ mtg)
{
    int t = threadIdx.x;
    if (blockIdx.x == 0) {
        __shared__ int sm[256];
        int hv[NCHUNK];
        int tot = 0;
        if (t < nbk) {
#pragma unroll
            for (int c = 0; c < NCHUNK; ++c) hv[c] = H[c * nbk + t];
#pragma unroll
            for (int c = 0; c < NCHUNK; ++c) tot += hv[c];
        }
        sm[t] = tot;
        __syncthreads();
        for (int off = 1; off < 256; off <<= 1) {
            int x = (t >= off) ? sm[t - off] : 0;
            __syncthreads();
            sm[t] += x;
            __syncthreads();
        }
        int excl = sm[t] - tot;
        if (t < nbk) {
            bktstart[t] = excl;
            int run = excl;
#pragma unroll
            for (int c = 0; c < NCHUNK; ++c) { base[c * nbk + t] = run; run += hv[c]; }
        }
        if (t == 0) { bktstart[nbk] = E; rowptr[nbk * 256] = E; }
    } else {
        int i = (blockIdx.x - 1) * 256 + t;
        if (i < 16384) {
            int c = i >> 7, k = i & 127;
            int h = c >> 4, o = c & 15;
            wt[i] = (_Float16)w0[h * 2048 + k * 16 + o];
        } else if (i < 16384 + 2048) {
            int m = i - 16384;
            int j = m >> 7, k = m & 127;
            int h = j & 7;
            const float* av = (j < 8) ? asrc0 : atrg0;
            float s = 0.f;
#pragma unroll
            for (int o = 0; o < 16; ++o) s += w0[h * 2048 + k * 16 + o] * av[h * 16 + o];
            mtg[m] = (_Float16)s;
        }
    }
}

// K3: scatter packed (src | (trg&255)<<16) bucket-major via LDS cursors
__global__ __launch_bounds__(1024) void sort_scatter_kernel(
    const int* __restrict__ src, const int* __restrict__ trg,
    const int* __restrict__ base, unsigned int* __restrict__ stage,
    int E, int nbk, int chunk)
{
    __shared__ int cur[256];
    int c = blockIdx.x, t = threadIdx.x;
    if (t < nbk) cur[t] = base[c * nbk + t];
    __syncthreads();
    int e0 = c * chunk, e1 = min(e0 + chunk, E);
    for (int i = e0 + t; i < e1; i += 1024) {
        int tg = trg[i];
        int pos = atomicAdd(&cur[tg >> 8], 1);
        stage[pos] = (unsigned int)src[i] | ((unsigned int)(tg & 255) << 16);
    }
}

__device__ __forceinline__ v8h cvt8(float4 lo, float4 hi) {
    v8h r;
    r[0] = (_Float16)lo.x; r[1] = (_Float16)lo.y; r[2] = (_Float16)lo.z; r[3] = (_Float16)lo.w;
    r[4] = (_Float16)hi.x; r[5] = (_Float16)hi.y; r[6] = (_Float16)hi.z; r[7] = (_Float16)hi.w;
    return r;
}

// K4: blocks 0..nbk-1 = finalize (bucket CSR); blocks nbk.. = MFMA gemm0.
__global__ __launch_bounds__(256) void finalize_gemm0_kernel(
    const unsigned int* __restrict__ stage, const int* __restrict__ bktstart,
    int* __restrict__ rowptr, int* __restrict__ colsrc, int nbk,
    const float* __restrict__ stat, const float* __restrict__ dyn0,
    const float* __restrict__ dyn1, const float4* __restrict__ wt4g,
    const _Float16* __restrict__ mtg,
    unsigned char* __restrict__ hp8, float* __restrict__ s0, float* __restrict__ t0,
    int n_nodes)
{
    __shared__ char smem[32768];
    int t = threadIdx.x;
    if ((int)blockIdx.x < nbk) {
        int* hist = (int*)smem;
        int* sm   = hist + 256;
        int* cur  = sm + 256;
        int b = blockIdx.x;
        int s0i = bktstart[b], cnt = bktstart[b + 1] - s0i;
        hist[t] = 0;
        __syncthreads();
        for (int i = t; i < cnt; i += 256)
            atomicAdd(&hist[stage[s0i + i] >> 16], 1);
        __syncthreads();
        int h = hist[t];
        sm[t] = h;
        __syncthreads();
        for (int off = 1; off < 256; off <<= 1) {
            int x = (t >= off) ? sm[t - off] : 0;
            __syncthreads();
            sm[t] += x;
            __syncthreads();
        }
        int excl = sm[t] - h;
        cur[t] = s0i + excl;
        rowptr[b * 256 + t] = s0i + excl;
        __syncthreads();
        for (int i = t; i < cnt; i += 256) {
            unsigned int p = stage[s0i + i];
            int pos = atomicAdd(&cur[p >> 16], 1);
            colsrc[pos] = (int)(p & 0xFFFFu);
        }
    } else {
        char* wt_s = smem;   // 128 rows (c) x 256B, XOR-swizzled
        int nb = (blockIdx.x - nbk) * 64;

#pragma unroll
        for (int j = 0; j < 8; ++j) {
            int i = t + j * 256;
            int c = i >> 4;
            int dst = (i * 16) ^ ((c & 7) << 4);
            *reinterpret_cast<float4*>(wt_s + dst) = wt4g[i];
        }
        __syncthreads();

        int l = t & 63, w = t >> 6;
        int cl = l & 15, klo = l >> 4;
        int rowbase = w * 16;
        int rg = min(nb + rowbase + cl, n_nodes - 1);

        v8h a[4];
        {
            float4 lo, hi;
            lo = *reinterpret_cast<const float4*>(&dyn0[(size_t)rg * 32 + klo * 8]);
            hi = *reinterpret_cast<const float4*>(&dyn0[(size_t)rg * 32 + klo * 8 + 4]);
            a[0] = cvt8(lo, hi);
            lo = *reinterpret_cast<const float4*>(&dyn1[(size_t)rg * 32 + klo * 8]);
            hi = *reinterpret_cast<const float4*>(&dyn1[(size_t)rg * 32 + klo * 8 + 4]);
            a[1] = cvt8(lo, hi);
            lo = *reinterpret_cast<const float4*>(&stat[(size_t)rg * 64 + klo * 8]);
            hi = *reinterpret_cast<const float4*>(&stat[(size_t)rg * 64 + klo * 8 + 4]);
            a[2] = cvt8(lo, hi);
            lo = *reinterpret_cast<const float4*>(&stat[(size_t)rg * 64 + 32 + klo * 8]);
            hi = *reinterpret_cast<const float4*>(&stat[(size_t)rg * 64 + 32 + klo * 8 + 4]);
            a[3] = cvt8(lo, hi);
        }

        f32x4 sacc = {0.f, 0.f, 0.f, 0.f};
#pragma unroll
        for (int kk = 0; kk < 4; ++kk) {
            v8h b = *reinterpret_cast<const v8h*>(&mtg[(size_t)cl * 128 + kk * 32 + klo * 8]);
            sacc = __builtin_amdgcn_mfma_f32_16x16x32_f16(a[kk], b, sacc, 0, 0, 0);
        }

        f32x4 acc[8];
#pragma unroll
        for (int cb = 0; cb < 8; ++cb) {
            f32x4 c = {0.f, 0.f, 0.f, 0.f};
#pragma unroll
            for (int kk = 0; kk < 4; ++kk) {
                int cc = cb * 16 + cl;
                int byte = (cc * 256 + kk * 64 + klo * 16) ^ ((cl & 7) << 4);
                v8h b = *reinterpret_cast<const v8h*>(wt_s + byte);
                c = __builtin_amdgcn_mfma_f32_16x16x32_f16(a[kk], b, c, 0, 0, 0);
            }
            acc[cb] = c;
        }

#pragma unroll
        for (int r = 0; r < 4; ++r) {
            int node = nb + rowbase + klo * 4 + r;
            if (node < n_nodes) {
#pragma unroll
                for (int cb = 0; cb < 8; ++cb) {
                    int wv = __builtin_amdgcn_cvt_pk_fp8_f32(acc[cb][r], 0.f, 0, false);
                    hp8[(size_t)node * 128 + cb * 16 + cl] = (unsigned char)(wv & 0xFF);
                }
                if (cl < 8) s0[node * 8 + cl]     = sacc[r];
                else        t0[node * 8 + cl - 8] = sacc[r];
            }
        }
    }
}

// ---------------- Layer-0 aggregate: one WAVE per target node ----------------
// fp8 gather; MAC loop software-pipelined 1 pair ahead (uint regs, +2 VGPR).
#define CH 64
__global__ __launch_bounds__(256) void node_accum0_kernel(
    const int* __restrict__ rowptr, const int* __restrict__ colsrc,
    const float* __restrict__ s0, const float* __restrict__ t0,
    const unsigned char* __restrict__ hp8, const float* __restrict__ w1,
    const float* __restrict__ asrc1, const float* __restrict__ atrg1,
    float4* __restrict__ pk1, float* __restrict__ t1, int n_nodes)
{
    __shared__ int   se_s[4][CH];
    __shared__ float p_s[4][CH * 8];

    int w = threadIdx.x >> 6;
    int l = threadIdx.x & 63;
    int n = blockIdx.x * 4 + w;
    if (n >= n_nodes) return;

    int start = rowptr[n];
    int deg = rowptr[n + 1] - start;
    int hl = l & 7;
    int g  = l >> 5;
    int j  = l & 31;
    int hc2 = j >> 2;
    float tval = t0[n * 8 + hl];
    const float* pw = p_s[w];

    float a0 = 0.f, a1 = 0.f, a2 = 0.f, a3 = 0.f, dsum = 0.f;
    for (int chunk = 0; chunk < deg; chunk += CH) {
        int m = min(CH, deg - chunk);
        se_s[w][l] = (l < m) ? colsrc[start + chunk + l] : 0;
        __builtin_amdgcn_wave_barrier();
        int iters = (m + 7) >> 3;
        for (int r = 0; r < iters; ++r) {
            int e = r * 8 + (l >> 3);
            float p = 0.f;
            if (e < m) {
                int se = se_s[w][e];
                float x = s0[se * 8 + hl] + tval;
                p = __expf(lrelu02(x) - ESHIFT);
            }
            p_s[w][r * 64 + l] = p;
            dsum += p;
        }
        __builtin_amdgcn_wave_barrier();

        int e = 0;
        if (m >= 4) {
            // software pipeline: keep the NEXT pair's loads in flight
            unsigned int va = *reinterpret_cast<const unsigned int*>(
                &hp8[(size_t)se_s[w][e + g] * 128 + j * 4]);
            unsigned int vb = *reinterpret_cast<const unsigned int*>(
                &hp8[(size_t)se_s[w][e + 2 + g] * 128 + j * 4]);
            for (; e + 4 <= m; e += 4) {
                unsigned int na = 0, nb2 = 0;
                if (e + 8 <= m) {
                    na = *reinterpret_cast<const unsigned int*>(
                        &hp8[(size_t)se_s[w][e + 4 + g] * 128 + j * 4]);
                    nb2 = *reinterpret_cast<const unsigned int*>(
                        &hp8[(size_t)se_s[w][e + 6 + g] * 128 + j * 4]);
                }
                float pa = pw[(e + g) * 8 + hc2];
                float pb = pw[(e + 2 + g) * 8 + hc2];
                f32x2 la = __builtin_amdgcn_cvt_pk_f32_fp8((int)va, false);
                f32x2 ha = __builtin_amdgcn_cvt_pk_f32_fp8((int)va, true);
                f32x2 lb = __builtin_amdgcn_cvt_pk_f32_fp8((int)vb, false);
                f32x2 hb = __builtin_amdgcn_cvt_pk_f32_fp8((int)vb, true);
                a0 += la[0] * pa; a1 += la[1] * pa; a2 += ha[0] * pa; a3 += ha[1] * pa;
                a0 += lb[0] * pb; a1 += lb[1] * pb; a2 += hb[0] * pb; a3 += hb[1] * pb;
                va = na; vb = nb2;
            }
        }
        for (; e < m; e += 2) {
            int ee = e + g;
            int se = se_s[w][ee];
            unsigned int v = *reinterpret_cast<const unsigned int*>(&hp8[(size_t)se * 128 + j * 4]);
            float p = pw[ee * 8 + hc2];
            f32x2 lo = __builtin_amdgcn_cvt_pk_f32_fp8((int)v, false);
            f32x2 hi = __builtin_amdgcn_cvt_pk_f32_fp8((int)v, true);
            a0 += lo[0] * p; a1 += lo[1] * p; a2 += hi[0] * p; a3 += hi[1] * p;
        }
        __builtin_amdgcn_wave_barrier();
    }

    a0 += __shfl_xor(a0, 32);
    a1 += __shfl_xor(a1, 32);
    a2 += __shfl_xor(a2, 32);
    a3 += __shfl_xor(a3, 32);

    dsum += __shfl_xor(dsum, 8);
    dsum += __shfl_xor(dsum, 16);
    dsum += __shfl_xor(dsum, 32);
    float denom = __shfl(dsum, hc2);
    float inv = 1.f / (denom + 1e-16f);
    float v0 = a0 * inv; v0 = v0 > 0.f ? v0 : expm1f(v0);
    float v1 = a1 * inv; v1 = v1 > 0.f ? v1 : expm1f(v1);
    float v2 = a2 * inv; v2 = v2 > 0.f ? v2 : expm1f(v2);
    float v3 = a3 * inv; v3 = v3 > 0.f ? v3 : expm1f(v3);

    float4 wv0 = *reinterpret_cast<const float4*>(&w1[j * 8]);
    float4 wv1 = *reinterpret_cast<const float4*>(&w1[j * 8 + 4]);
    float r0 = v0 * wv0.x + v1 * wv0.z + v2 * wv1.x + v3 * wv1.z;
    float r1 = v0 * wv0.y + v1 * wv0.w + v2 * wv1.y + v3 * wv1.w;
#pragma unroll
    for (int off = 16; off > 0; off >>= 1) {
        r0 += __shfl_down(r0, off);
        r1 += __shfl_down(r1, off);
    }
    if (l == 0) {
        float s1v = r0 * asrc1[0] + r1 * asrc1[1];
        float t1v = r0 * atrg1[0] + r1 * atrg1[1];
        float4 pk; pk.x = r0; pk.y = r1; pk.z = s1v; pk.w = 0.f;
        pk1[n] = pk;
        t1[n] = t1v;
    }
}

// ---------------- Layer-1 aggregate: 16 LANES per node (mean deg = 16) ----------
__global__ __launch_bounds__(256) void node_accum1_kernel(
    const int* __restrict__ rowptr, const int* __restrict__ colsrc,
    const float4* __restrict__ pk1, const float* __restrict__ t1,
    float* __restrict__ out, int n_nodes)
{
    int lane = threadIdx.x & 15;
    int n = blockIdx.x * 16 + (threadIdx.x >> 4);
    if (n >= n_nodes) return;
    int start = rowptr[n], deg = rowptr[n + 1] - start;
    float tn = t1[n];
    float d = 0.f, a0 = 0.f, a1 = 0.f;
    for (int i = lane; i < deg; i += 16) {
        int se = colsrc[start + i];
        float4 q = pk1[se];
        float p = __expf(lrelu02(q.z + tn) - ESHIFT);
        d += p;
        a0 += p * q.x;
        a1 += p * q.y;
    }
#pragma unroll
    for (int off = 8; off > 0; off >>= 1) {
        d  += __shfl_xor(d, off);
        a0 += __shfl_xor(a0, off);
        a1 += __shfl_xor(a1, off);
    }
    if (lane == 0) {
        float inv = 1.f / (d + 1e-16f);
        float x0 = a0 * inv, x1 = a1 * inv;
        float m = fmaxf(x0, x1);
        float lse = m + logf(__expf(x0 - m) + __expf(x1 - m));
        out[n * 2 + 0] = x0 - lse;
        out[n * 2 + 1] = x1 - lse;
    }
}

extern "C" void kernel_launch(void* const* d_in, const int* in_sizes, int n_in,
                              void* d_out, int out_size, void* d_ws, size_t ws_size,
                              hipStream_t stream) {
    const float* stat  = (const float*)d_in[0];
    const float* dyn0  = (const float*)d_in[1];
    const float* dyn1  = (const float*)d_in[2];
    const int*   src   = (const int*)d_in[3];
    const int*   trg   = (const int*)d_in[4];
    const float* w0    = (const float*)d_in[5];
    const float* asrc0 = (const float*)d_in[6];
    const float* atrg0 = (const float*)d_in[7];
    const float* w1    = (const float*)d_in[8];
    const float* asrc1 = (const float*)d_in[9];
    const float* atrg1 = (const float*)d_in[10];
    float* out = (float*)d_out;

    const int N = in_sizes[0] / 64;   // 50000 (src fits 16 bits)
    const int E = in_sizes[3];        // 800000
    const int NBK = (N + 255) >> 8;   // 196 buckets of 256 nodes
    const int CHUNK = (E + NCHUNK - 1) / NCHUNK;
    const int NTB = (N + 63) >> 6;    // 782 gemm0 tiles (64 nodes each)

    // ---- workspace layout (all regions dedicated, no aliasing) ----
    float* ws = (float*)d_ws;
    size_t off = 0;
    unsigned char* hp8 = (unsigned char*)(ws + off); off += (size_t)N * 32;  // 6.4MB fp8
    unsigned int* stage = (unsigned int*)(ws + off); off += (size_t)E;       // 3.2MB packed
    float* s0  = ws + off; off += (size_t)N * 8;
    float* t0  = ws + off; off += (size_t)N * 8;
    float4* pk1 = (float4*)(ws + off); off += (size_t)N * 4;
    float* t1  = ws + off; off += (size_t)N;
    _Float16* wt  = (_Float16*)(ws + off); off += 8192;   // 32KB fp16 W^T [c][k]
    _Float16* mtg = (_Float16*)(ws + off); off += 1024;   // 4KB fp16 Bs^T [j][k]
    off = (off + 3) & ~(size_t)3;
    int* iws      = (int*)(ws + off);
    int* rowptr   = iws;                        // NBK*256 + 1
    int* colsrc   = rowptr + NBK * 256 + 1;     // E
    int* H        = colsrc + E;                 // NCHUNK*NBK
    int* basearr  = H + NCHUNK * NBK;           // NCHUNK*NBK
    int* bktstart = basearr + NCHUNK * NBK;     // NBK+1

    // K1: per-chunk bucket histogram
    sort_hist_kernel<<<NCHUNK, 1024, 0, stream>>>(trg, H, E, NBK, CHUNK);
    // K2: bucket scan (block 0) || W pre-pack (blocks 1..72)
    scan_wconv_kernel<<<73, 256, 0, stream>>>(
        H, basearr, bktstart, rowptr, NBK, E, w0, asrc0, atrg0, wt, mtg);
    // K3: bucket-major packed-pair scatter
    sort_scatter_kernel<<<NCHUNK, 1024, 0, stream>>>(src, trg, basearr, stage, E, NBK, CHUNK);
    // K4: per-bucket CSR finalize (blocks 0..NBK-1) || MFMA gemm0 (blocks NBK..)
    finalize_gemm0_kernel<<<NBK + NTB, 256, 0, stream>>>(
        stage, bktstart, rowptr, colsrc, NBK,
        stat, dyn0, dyn1, (const float4*)wt, mtg, hp8, s0, t0, N);
    // K5: layer-0 aggregate + ELU + W1 + layer-1 scores
    node_accum0_kernel<<<(N + 3) / 4, 256, 0, stream>>>(
        rowptr, colsrc, s0, t0, hp8, w1, asrc1, atrg1, pk1, t1, N);
    // K6: layer-1 aggregate + mean + log_softmax
    node_accum1_kernel<<<(N + 15) / 16, 256, 0, stream>>>(
        rowptr, colsrc, pk1, t1, out, N);
}